// Round 5
// baseline (405.128 us; speedup 1.0000x reference)
//
#include <hip/hip_runtime.h>
#include <math.h>

#define EMBED 1024
#define SEQ   2048
#define HEAD  64
#define NROW  8192   /* BATCH*SEQ */

// ---------------------------------------------------------------------------
// Round 5: structural fixes, still all-f32 VALU.
//  K1 qkv_proj (fused): one block = 32 rows x all 192 output cols, full K.
//     - x read ONCE (32 MB), W L2-resident, P written once (6.3 MB, no K-split)
//     - wave-specialized columns: wave w owns cols [48w,48w+48) -> W tile read
//       from LDS exactly once per wave (minimal LDS amplification)
//     - T14 async staging: global->reg issued before compute, ds_write after
//     - XOR swizzle on x tile: chunk = kk4 ^ (r&7) ^ (r>>3) -> 4 row-groups
//       land in distinct bank quads (read pattern is 4-distinct x 16-broadcast)
//  K2 attn: single P source, ping-pong K/V LDS buffers with register prefetch,
//     interior barrier removed (ps[] is wave-private).
// ---------------------------------------------------------------------------

__global__ __launch_bounds__(256)
void qkv_proj(const float* __restrict__ x,
              const float* __restrict__ Wq,
              const float* __restrict__ Wk,
              const float* __restrict__ Wv,
              float* __restrict__ P)
{
    const int tid  = threadIdx.x;
    const int w    = tid >> 6;        // wave 0..3 -> col block 48w
    const int lane = tid & 63;
    const int tx   = lane & 15;       // col within 16-group
    const int ty   = lane >> 4;       // row group 0..3 (8 rows each)
    const int row0 = blockIdx.x * 32;

    __shared__ float xs [2][32 * 36];
    __shared__ float wsm[2][192 * 36];

    const float* Wm[3] = {Wq, Wk, Wv};

    // staging identities
    const int xr = tid >> 3;          // 0..31  x row
    const int xc = tid & 7;           // 0..7   float4 chunk
    const int xswz = ((xr & 7) ^ (xr >> 3)) & 7;

    float4 xg;                        // staged x float4
    float4 wg[6];                     // staged W float4s

    // ---- prologue: load + commit chunk 0 ----
    {
        xg = *(const float4*)&x[(size_t)(row0 + xr) * EMBED + xc * 4];
#pragma unroll
        for (int p = 0; p < 6; ++p) {
            const int wrow = (tid >> 3) + 32 * (p & 1);
            wg[p] = *(const float4*)&Wm[p >> 1][(size_t)wrow * EMBED + xc * 4];
        }
        *(float4*)&xs[0][xr * 36 + ((xc ^ xswz) & 7) * 4] = xg;
#pragma unroll
        for (int p = 0; p < 6; ++p) {
            const int col = (tid >> 3) + 32 * p;
            *(float4*)&wsm[0][col * 36 + xc * 4] = wg[p];
        }
    }
    __syncthreads();

    float acc[8][3];
#pragma unroll
    for (int i = 0; i < 8; ++i)
#pragma unroll
        for (int jj = 0; jj < 3; ++jj) acc[i][jj] = 0.f;

    const int wcol0 = w * 48 + tx;

    for (int c = 0; c < 32; ++c) {
        const int cur = c & 1;
        // ---- issue next chunk's global loads (latency hidden under compute)
        if (c + 1 < 32) {
            const int k0 = (c + 1) * 32;
            xg = *(const float4*)&x[(size_t)(row0 + xr) * EMBED + k0 + xc * 4];
#pragma unroll
            for (int p = 0; p < 6; ++p) {
                const int wrow = (tid >> 3) + 32 * (p & 1);
                wg[p] = *(const float4*)&Wm[p >> 1][(size_t)wrow * EMBED + k0 + xc * 4];
            }
        }
        // ---- compute on current buffer ----
        const float* xb = xs[cur];
        const float* wb = wsm[cur];
#pragma unroll
        for (int kk4 = 0; kk4 < 8; ++kk4) {
            float4 bb[3];
#pragma unroll
            for (int jj = 0; jj < 3; ++jj)
                bb[jj] = *(const float4*)&wb[(wcol0 + 16 * jj) * 36 + kk4 * 4];
#pragma unroll
            for (int i = 0; i < 8; ++i) {
                const int r  = ty * 8 + i;
                const int ch = (kk4 ^ i ^ ty) & 7;      // swz(r)=i^ty
                float4 a = *(const float4*)&xb[r * 36 + ch * 4];
#pragma unroll
                for (int jj = 0; jj < 3; ++jj)
                    acc[i][jj] += a.x * bb[jj].x + a.y * bb[jj].y
                                + a.z * bb[jj].z + a.w * bb[jj].w;
            }
        }
        // ---- commit staged regs to the other buffer ----
        if (c + 1 < 32) {
            const int nxt = cur ^ 1;
            *(float4*)&xs[nxt][xr * 36 + ((xc ^ xswz) & 7) * 4] = xg;
#pragma unroll
            for (int p = 0; p < 6; ++p) {
                const int col = (tid >> 3) + 32 * p;
                *(float4*)&wsm[nxt][col * 36 + xc * 4] = wg[p];
            }
        }
        __syncthreads();
    }

    // ---- epilogue: P[which][row][h] ----
#pragma unroll
    for (int jj = 0; jj < 3; ++jj) {
        const int col   = wcol0 + 16 * jj;
        const int which = col >> 6;
        const int h     = col & 63;
#pragma unroll
        for (int i = 0; i < 8; ++i)
            P[((size_t)which * NROW + row0 + ty * 8 + i) * HEAD + h] = acc[i][jj];
    }
}

// ---------------------------------------------------------------------------
// Attention: 16 q-rows per block, 4 waves x 4 rows, 64-key tiles, ping-pong
// LDS K/V buffers with register prefetch (T14).
// lane = dg*16 + kk ; kk = key mod 16, dg = 16-dim group AND j-slot (key/16).
// ---------------------------------------------------------------------------

__global__ __launch_bounds__(256)
void attn(const float* __restrict__ P, float* __restrict__ out)
{
    const int bi = blockIdx.x;  // 0..511, balanced causal pairing
    int b, t16;
    if (bi < 256) { b = bi >> 7;            t16 = bi & 127; }
    else          { int j = bi - 256; b = 2 + (j >> 7); t16 = 127 - (j & 127); }
    const int q0 = t16 * 16;

    const int tid  = threadIdx.x;
    const int w    = tid >> 6;      // wave 0..3
    const int lane = tid & 63;
    const int kk   = lane & 15;
    const int dg   = lane >> 4;
    const int sw   = kk & 7;        // LDS chunk swizzle key

    const float* Pq = P;
    const float* Pk = P + (size_t)1 * NROW * HEAD;
    const float* Pv = P + (size_t)2 * NROW * HEAD;

    __shared__ float Ks[2][64 * 64];
    __shared__ float Vs[2][64 * 64];
    __shared__ float ps[4][4][64];   // [wave][row][key] (wave-private)
    __shared__ float obuf[16 * 64];

    // ---- Q into registers (fold in the *32 scale) ----
    float4 qv[4][4];
    int qrow[4];
#pragma unroll
    for (int r = 0; r < 4; ++r) {
        qrow[r] = q0 + 4 * w + r;
        const size_t base = ((size_t)b * SEQ + qrow[r]) * HEAD + dg * 16;
#pragma unroll
        for (int c = 0; c < 4; ++c) {
            float4 a0 = *(const float4*)&Pq[base + c * 4];
            qv[r][c] = make_float4(32.f * a0.x, 32.f * a0.y, 32.f * a0.z, 32.f * a0.w);
        }
    }

    float m[4], l[4];
    float4 po[4][4];
#pragma unroll
    for (int r = 0; r < 4; ++r) {
        m[r] = -1e30f; l[r] = 0.f;
#pragma unroll
        for (int c = 0; c < 4; ++c) po[r][c] = make_float4(0.f, 0.f, 0.f, 0.f);
    }

    const int ntiles = q0 / 64 + 1;

    // staging identities
    const int skey = (tid & 255) >> 4;   // base key row per pp chunk step 16
    float4 kreg[4], vreg[4];

    // ---- prologue: prefetch + commit tile 0 ----
#pragma unroll
    for (int pp = 0; pp < 4; ++pp) {
        const int idx = pp * 256 + tid;
        const int key = idx >> 4, c4 = idx & 15;
        const size_t g = ((size_t)b * SEQ + key) * HEAD + c4 * 4;
        kreg[pp] = *(const float4*)&Pk[g];
        vreg[pp] = *(const float4*)&Pv[g];
    }
#pragma unroll
    for (int pp = 0; pp < 4; ++pp) {
        const int idx = pp * 256 + tid;
        const int key = idx >> 4, c4 = idx & 15, cc = c4 ^ (key & 7);
        *(float4*)&Ks[0][key * 64 + cc * 4] = kreg[pp];
        *(float4*)&Vs[0][key * 64 + cc * 4] = vreg[pp];
    }
    __syncthreads();

    for (int kt = 0; kt < ntiles; ++kt) {
        const int cur   = kt & 1;
        const int kbase = kt * 64;

        // ---- issue next tile's global loads ----
        if (kt + 1 < ntiles) {
            const int nb = (kt + 1) * 64;
#pragma unroll
            for (int pp = 0; pp < 4; ++pp) {
                const int idx = pp * 256 + tid;
                const int key = idx >> 4, c4 = idx & 15;
                const size_t g = ((size_t)b * SEQ + nb + key) * HEAD + c4 * 4;
                kreg[pp] = *(const float4*)&Pk[g];
                vreg[pp] = *(const float4*)&Pv[g];
            }
        }

        // ---- QK^T : s[r][j] = Q[row_r] . K[kk+16j] (partial over dg dims) --
        const float* Kb = Ks[cur];
        const float* Vb = Vs[cur];
        float s[4][4];
#pragma unroll
        for (int j = 0; j < 4; ++j) {
            const int krow = (kk + 16 * j) * 64;
            float4 kf[4];
#pragma unroll
            for (int q = 0; q < 4; ++q)
                kf[q] = *(const float4*)&Kb[krow + ((dg * 4 + q) ^ sw) * 4];
#pragma unroll
            for (int r = 0; r < 4; ++r) {
                float a = 0.f;
#pragma unroll
                for (int q = 0; q < 4; ++q)
                    a += qv[r][q].x * kf[q].x + qv[r][q].y * kf[q].y
                       + qv[r][q].z * kf[q].z + qv[r][q].w * kf[q].w;
                s[r][j] = a;
            }
        }
#pragma unroll
        for (int r = 0; r < 4; ++r)
#pragma unroll
            for (int j = 0; j < 4; ++j) {
                float v = s[r][j];
                v += __shfl_xor(v, 16);
                v += __shfl_xor(v, 32);
                s[r][j] = v;
            }

        // ---- online softmax (lane == key within tile) ----
        const int keyg = kbase + lane;
#pragma unroll
        for (int r = 0; r < 4; ++r) {
            float sl = (dg == 0) ? s[r][0] : (dg == 1) ? s[r][1]
                     : (dg == 2) ? s[r][2] : s[r][3];
            float sv = (keyg <= qrow[r]) ? sl : -1e30f;
            float tmax = sv;
#pragma unroll
            for (int off = 1; off < 64; off <<= 1)
                tmax = fmaxf(tmax, __shfl_xor(tmax, off));
            const float mnew = fmaxf(m[r], tmax);
            const float fac  = __expf(m[r] - mnew);
            const float pv   = __expf(sv - mnew);
            float psum = pv;
#pragma unroll
            for (int off = 1; off < 64; off <<= 1)
                psum += __shfl_xor(psum, off);
            l[r] = l[r] * fac + psum;
            m[r] = mnew;
#pragma unroll
            for (int c = 0; c < 4; ++c) {
                po[r][c].x *= fac; po[r][c].y *= fac;
                po[r][c].z *= fac; po[r][c].w *= fac;
            }
            ps[w][r][lane] = pv;   // wave-private; lgkmcnt orders RAW below
        }

        // ---- PV : po[r][q] += sum_j p[r][kk+16j] * V[kk+16j][dg dims] ----
#pragma unroll
        for (int j = 0; j < 4; ++j) {
            const int key  = kk + 16 * j;
            const int krow = key * 64;
            float4 vf[4];
#pragma unroll
            for (int q = 0; q < 4; ++q)
                vf[q] = *(const float4*)&Vb[krow + ((dg * 4 + q) ^ sw) * 4];
            float pj[4];
#pragma unroll
            for (int r = 0; r < 4; ++r) pj[r] = ps[w][r][key];
#pragma unroll
            for (int r = 0; r < 4; ++r)
#pragma unroll
                for (int q = 0; q < 4; ++q) {
                    po[r][q].x += pj[r] * vf[q].x;
                    po[r][q].y += pj[r] * vf[q].y;
                    po[r][q].z += pj[r] * vf[q].z;
                    po[r][q].w += pj[r] * vf[q].w;
                }
        }

        // ---- commit prefetched tile to the other buffer ----
        if (kt + 1 < ntiles) {
            const int nxt = cur ^ 1;
#pragma unroll
            for (int pp = 0; pp < 4; ++pp) {
                const int idx = pp * 256 + tid;
                const int key = idx >> 4, c4 = idx & 15, cc = c4 ^ (key & 7);
                *(float4*)&Ks[nxt][key * 64 + cc * 4] = kreg[pp];
                *(float4*)&Vs[nxt][key * 64 + cc * 4] = vreg[pp];
            }
        }
        __syncthreads();
    }

    // ---- reduce po across the 16 kk lanes ----
#pragma unroll
    for (int r = 0; r < 4; ++r)
#pragma unroll
        for (int q = 0; q < 4; ++q) {
            float4 v = po[r][q];
#pragma unroll
            for (int off = 1; off < 16; off <<= 1) {
                v.x += __shfl_xor(v.x, off);
                v.y += __shfl_xor(v.y, off);
                v.z += __shfl_xor(v.z, off);
                v.w += __shfl_xor(v.w, off);
            }
            po[r][q] = v;
        }

    if (kk == 0) {
#pragma unroll
        for (int r = 0; r < 4; ++r) {
            const float inv = 1.0f / l[r];
#pragma unroll
            for (int q = 0; q < 4; ++q) {
                float4 v = po[r][q];
                v.x *= inv; v.y *= inv; v.z *= inv; v.w *= inv;
                *(float4*)&obuf[(4 * w + r) * 64 + dg * 16 + q * 4] = v;
            }
        }
    }
    __syncthreads();

    const int row = tid >> 4, c4 = tid & 15;
    *(float4*)&out[((size_t)b * SEQ + q0 + row) * HEAD + c4 * 4] =
        *(const float4*)&obuf[row * 64 + c4 * 4];
}

// ---------------------------------------------------------------------------

extern "C" void kernel_launch(void* const* d_in, const int* in_sizes, int n_in,
                              void* d_out, int out_size, void* d_ws, size_t ws_size,
                              hipStream_t stream)
{
    // setup_inputs order: x, Wk, Wq, Wv
    const float* x  = (const float*)d_in[0];
    const float* Wk = (const float*)d_in[1];
    const float* Wq = (const float*)d_in[2];
    const float* Wv = (const float*)d_in[3];
    float* P = (float*)d_ws;              // 3*8192*64 f32 = 6.3 MB (Q,K,V)

    qkv_proj<<<dim3(256), 256, 0, stream>>>(x, Wq, Wk, Wv, P);
    attn<<<dim3(512), 256, 0, stream>>>(P, (float*)d_out);
}

// Round 6
// 297.793 us; speedup vs baseline: 1.3604x; 1.3604x over previous
//
#include <hip/hip_runtime.h>
#include <math.h>

#define EMBED 1024
#define SEQ   2048
#define HEAD  64
#define NROW  8192   /* BATCH*SEQ */

// ---------------------------------------------------------------------------
// Round 6:
//  K0 prep_w:   split W (f32) -> Whi/Wlo bf16, rows ordered [Q;K;V] (192x1024).
//  K1 qkv_mfma: split-bf16 MFMA GEMM (3 MFMAs per frag: hh + hl + lh).
//               256 blocks x 512 thr; 8 waves = 2 K-groups x 4 col-groups;
//               in-block K-split reduce via LDS. Precision: err ~2^-18 rel.
//  K2 attn_partial: uniform work items = (16-row q-tile, <=8 key-tile chunk),
//               1280 blocks; softmax pv kept IN REGISTERS (no ps LDS at all);
//               partials (po,m,l) to workspace.
//  K3 attn_combine: rescale+merge <=4 partials per q-tile, normalize, write.
// ws layout: P 6.29MB | Whl 0.79MB | PT 5.41MB  (total 12.48MB)
// ---------------------------------------------------------------------------

typedef float f32x4  __attribute__((ext_vector_type(4)));
typedef short bf16x8 __attribute__((ext_vector_type(8)));

__device__ __forceinline__ ushort f2bf(float v) {
    union { float f; unsigned u; } t; t.f = v;
    unsigned r = t.u + 0x7FFFu + ((t.u >> 16) & 1u);   // RNE
    return (ushort)(r >> 16);
}
__device__ __forceinline__ float bf2f(ushort h) {
    union { float f; unsigned u; } t; t.u = ((unsigned)h) << 16;
    return t.f;
}

// ---------------------------------------------------------------------------
__global__ __launch_bounds__(256)
void prep_w(const float* __restrict__ Wq, const float* __restrict__ Wk,
            const float* __restrict__ Wv, ushort* __restrict__ Whl)
{
    const int idx = blockIdx.x * 256 + threadIdx.x;   // f4 index, 49152 total
    const int row = idx >> 8;                         // 0..191
    const int c4  = (idx & 255) * 4;
    const float* W = (row < 64) ? Wq : (row < 128) ? Wk : Wv;
    float4 v = *(const float4*)&W[(size_t)(row & 63) * EMBED + c4];
    float f[4] = {v.x, v.y, v.z, v.w};
    ushort h[4], l[4];
#pragma unroll
    for (int i = 0; i < 4; ++i) {
        h[i] = f2bf(f[i]);
        l[i] = f2bf(f[i] - bf2f(h[i]));
    }
    ushort4 H = make_ushort4(h[0], h[1], h[2], h[3]);
    ushort4 L = make_ushort4(l[0], l[1], l[2], l[3]);
    *(ushort4*)&Whl[(size_t)row * EMBED + c4]         = H;
    *(ushort4*)&Whl[(size_t)(192 + row) * EMBED + c4] = L;
}

// ---------------------------------------------------------------------------
// qkv via MFMA. Block: 32 rows x 192 cols, K=1024 split across 2 wave-groups.
// wave w: kg=w>>2 (K half), wq=w&3 (cols [48wq,48wq+48)); acc 2x3 frags.
// Frag layout (16x16x32 bf16): A/B lane l -> row l&15, k-octet 8*(l>>4);
// D lane l reg r -> row 4*(l>>4)+r, col l&15.
// ---------------------------------------------------------------------------
__global__ __launch_bounds__(512)
void qkv_mfma(const float* __restrict__ x,
              const ushort* __restrict__ Whl,
              float* __restrict__ P)
{
    __shared__ ushort Ah[2][32][40];    //  5,120 B  (pad 40: frag reads 2-way)
    __shared__ ushort Al[2][32][40];    //  5,120 B
    __shared__ ushort Bh[2][192][40];   // 30,720 B
    __shared__ ushort Bl[2][192][40];   // 30,720 B

    const int tid  = threadIdx.x;
    const int w    = tid >> 6;
    const int lane = tid & 63;
    const int kg   = w >> 2;
    const int wq   = w & 3;
    const int l15  = lane & 15, l4 = lane >> 4;
    const int row0 = blockIdx.x * 32;

    // staging identities
    const int arow = tid >> 4;          // 0..31
    const int aq   = tid & 15;
    const int ag   = aq >> 3, akq = aq & 7;

    f32x4 acc[2][3];
#pragma unroll
    for (int i = 0; i < 2; ++i)
#pragma unroll
        for (int j = 0; j < 3; ++j) acc[i][j] = (f32x4){0.f, 0.f, 0.f, 0.f};

    float4 xg;
    uint4  wg[6];
    int brow[6], bkq[6], bhl[6], bg[6];
#pragma unroll
    for (int s = 0; s < 6; ++s) {
        const int u = tid + 512 * s;    // 0..3071
        brow[s] = u >> 4;
        const int q = u & 15;
        bkq[s] = q & 3; bhl[s] = (q >> 2) & 1; bg[s] = q >> 3;
    }

    // ---- prologue: load + commit chunk 0 ----
    xg = *(const float4*)&x[(size_t)(row0 + arow) * EMBED + ag * 512 + akq * 4];
#pragma unroll
    for (int s = 0; s < 6; ++s)
        wg[s] = *(const uint4*)&Whl[(size_t)(bhl[s] * 192 + brow[s]) * EMBED
                                    + bg[s] * 512 + bkq[s] * 8];
    {
        float f[4] = {xg.x, xg.y, xg.z, xg.w};
        ushort h[4], l[4];
#pragma unroll
        for (int i = 0; i < 4; ++i) { h[i] = f2bf(f[i]); l[i] = f2bf(f[i] - bf2f(h[i])); }
        *(ushort4*)&Ah[ag][arow][akq * 4] = make_ushort4(h[0], h[1], h[2], h[3]);
        *(ushort4*)&Al[ag][arow][akq * 4] = make_ushort4(l[0], l[1], l[2], l[3]);
#pragma unroll
        for (int s = 0; s < 6; ++s) {
            ushort* dst = bhl[s] ? &Bl[bg[s]][brow[s]][bkq[s] * 8]
                                 : &Bh[bg[s]][brow[s]][bkq[s] * 8];
            *(uint4*)dst = wg[s];
        }
    }
    __syncthreads();

    for (int c = 0; c < 16; ++c) {
        // ---- issue next chunk's global loads ----
        if (c + 1 < 16) {
            const int k0 = (c + 1) * 32;
            xg = *(const float4*)&x[(size_t)(row0 + arow) * EMBED + ag * 512 + k0 + akq * 4];
#pragma unroll
            for (int s = 0; s < 6; ++s)
                wg[s] = *(const uint4*)&Whl[(size_t)(bhl[s] * 192 + brow[s]) * EMBED
                                            + bg[s] * 512 + k0 + bkq[s] * 8];
        }
        // ---- MFMA on current buffer ----
        {
            const int ko = 8 * l4;
            bf16x8 ah[2], alv[2], bhv[3], blv[3];
#pragma unroll
            for (int i = 0; i < 2; ++i) {
                ah[i]  = *(const bf16x8*)&Ah[kg][16 * i + l15][ko];
                alv[i] = *(const bf16x8*)&Al[kg][16 * i + l15][ko];
            }
#pragma unroll
            for (int j = 0; j < 3; ++j) {
                bhv[j] = *(const bf16x8*)&Bh[kg][48 * wq + 16 * j + l15][ko];
                blv[j] = *(const bf16x8*)&Bl[kg][48 * wq + 16 * j + l15][ko];
            }
#pragma unroll
            for (int i = 0; i < 2; ++i)
#pragma unroll
                for (int j = 0; j < 3; ++j) {
                    acc[i][j] = __builtin_amdgcn_mfma_f32_16x16x32_bf16(ah[i],  bhv[j], acc[i][j], 0, 0, 0);
                    acc[i][j] = __builtin_amdgcn_mfma_f32_16x16x32_bf16(ah[i],  blv[j], acc[i][j], 0, 0, 0);
                    acc[i][j] = __builtin_amdgcn_mfma_f32_16x16x32_bf16(alv[i], bhv[j], acc[i][j], 0, 0, 0);
                }
        }
        __syncthreads();
        // ---- commit staged regs ----
        if (c + 1 < 16) {
            float f[4] = {xg.x, xg.y, xg.z, xg.w};
            ushort h[4], l[4];
#pragma unroll
            for (int i = 0; i < 4; ++i) { h[i] = f2bf(f[i]); l[i] = f2bf(f[i] - bf2f(h[i])); }
            *(ushort4*)&Ah[ag][arow][akq * 4] = make_ushort4(h[0], h[1], h[2], h[3]);
            *(ushort4*)&Al[ag][arow][akq * 4] = make_ushort4(l[0], l[1], l[2], l[3]);
#pragma unroll
            for (int s = 0; s < 6; ++s) {
                ushort* dst = bhl[s] ? &Bl[bg[s]][brow[s]][bkq[s] * 8]
                                     : &Bh[bg[s]][brow[s]][bkq[s] * 8];
                *(uint4*)dst = wg[s];
            }
        }
        __syncthreads();
    }

    // ---- in-block K-group reduction (alias Bh as f32 scratch 32x192) ----
    __syncthreads();
    float* red = (float*)&Bh[0][0][0];
    if (kg == 1) {
#pragma unroll
        for (int i = 0; i < 2; ++i)
#pragma unroll
            for (int j = 0; j < 3; ++j)
#pragma unroll
                for (int r = 0; r < 4; ++r) {
                    const int rr = 16 * i + 4 * l4 + r;
                    const int cc = 48 * wq + 16 * j + l15;
                    red[rr * 192 + cc] = acc[i][j][r];
                }
    }
    __syncthreads();
    if (kg == 0) {
#pragma unroll
        for (int i = 0; i < 2; ++i)
#pragma unroll
            for (int j = 0; j < 3; ++j)
#pragma unroll
                for (int r = 0; r < 4; ++r) {
                    const int rr = 16 * i + 4 * l4 + r;
                    const int cc = 48 * wq + 16 * j + l15;
                    const float v = acc[i][j][r] + red[rr * 192 + cc];
                    const int which = cc >> 6, hh = cc & 63;
                    P[((size_t)which * NROW + row0 + rr) * HEAD + hh] = v;
                }
    }
}

// ---------------------------------------------------------------------------
// attn_partial: uniform items. item = (b, qt16, kc): <=8 key-tiles of 64.
// 4 waves x 4 rows; lane=(kk,dg); pv kept in registers (no ps LDS).
// Writes UNNORMALIZED po[16][64] + m[16] + l[16] at PT[item*1056].
// ---------------------------------------------------------------------------
__global__ __launch_bounds__(256)
void attn_partial(const float* __restrict__ P, float* __restrict__ PT)
{
    const int id = blockIdx.x;          // 0..1279
    const int b  = id / 320;
    const int f  = id - b * 320;
    int qt16, kc;
    if (f < 32)       { qt16 = f;                         kc = 0; }
    else if (f < 96)  { int t = f - 32;  qt16 = 32 + (t >> 1); kc = t & 1; }
    else if (f < 192) { int t = f - 96;  int u = t / 3; qt16 = 64 + u; kc = t - 3 * u; }
    else              { int t = f - 192; qt16 = 96 + (t >> 2); kc = t & 3; }

    const int q0 = qt16 * 16;
    const int nt = (qt16 >> 2) + 1;
    const int t0 = kc * 8;
    const int t1 = (t0 + 8 < nt) ? t0 + 8 : nt;

    const int tid  = threadIdx.x;
    const int w    = tid >> 6;
    const int lane = tid & 63;
    const int kk   = lane & 15;
    const int dg   = lane >> 4;
    const int sw   = kk & 7;

    const float* Pq = P;
    const float* Pk = P + (size_t)1 * NROW * HEAD;
    const float* Pv = P + (size_t)2 * NROW * HEAD;

    __shared__ float Ks[64 * 64];
    __shared__ float Vs[64 * 64];

    // ---- Q into registers (fold in the *32 scale) ----
    float4 qv[4][4];
    int qrow[4];
#pragma unroll
    for (int r = 0; r < 4; ++r) {
        qrow[r] = q0 + 4 * w + r;
        const size_t base = ((size_t)(b * SEQ + qrow[r])) * HEAD + dg * 16;
#pragma unroll
        for (int c = 0; c < 4; ++c) {
            float4 a = *(const float4*)&Pq[base + c * 4];
            qv[r][c] = make_float4(32.f * a.x, 32.f * a.y, 32.f * a.z, 32.f * a.w);
        }
    }

    float m[4], l[4];
    float4 po[4][4];
#pragma unroll
    for (int r = 0; r < 4; ++r) {
        m[r] = -1e30f; l[r] = 0.f;
#pragma unroll
        for (int c = 0; c < 4; ++c) po[r][c] = make_float4(0.f, 0.f, 0.f, 0.f);
    }

    for (int kt = t0; kt < t1; ++kt) {
        const int kbase = kt * 64;
        __syncthreads();
        // ---- stage K,V tile ----
#pragma unroll
        for (int pp = 0; pp < 4; ++pp) {
            const int idx = pp * 256 + tid;   // 0..1023
            const int key = idx >> 4;
            const int c4  = idx & 15;
            const int cc  = c4 ^ (key & 7);
            const size_t g = ((size_t)(b * SEQ + kbase + key)) * HEAD + c4 * 4;
            *(float4*)&Ks[key * 64 + cc * 4] = *(const float4*)&Pk[g];
            *(float4*)&Vs[key * 64 + cc * 4] = *(const float4*)&Pv[g];
        }
        __syncthreads();

        // ---- QK^T partial dots over dg dims ----
        float s[4][4];
#pragma unroll
        for (int j = 0; j < 4; ++j) {
            const int krow = (kk + 16 * j) * 64;
            float4 kf[4];
#pragma unroll
            for (int q = 0; q < 4; ++q)
                kf[q] = *(const float4*)&Ks[krow + ((dg * 4 + q) ^ sw) * 4];
#pragma unroll
            for (int r = 0; r < 4; ++r) {
                float a = 0.f;
#pragma unroll
                for (int q = 0; q < 4; ++q)
                    a += qv[r][q].x * kf[q].x + qv[r][q].y * kf[q].y
                       + qv[r][q].z * kf[q].z + qv[r][q].w * kf[q].w;
                s[r][j] = a;
            }
        }
#pragma unroll
        for (int r = 0; r < 4; ++r)
#pragma unroll
            for (int j = 0; j < 4; ++j) {
                float v = s[r][j];
                v += __shfl_xor(v, 16);
                v += __shfl_xor(v, 32);
                s[r][j] = v;
            }

        // ---- online softmax, pv in registers ----
        float pv[4][4];
#pragma unroll
        for (int r = 0; r < 4; ++r) {
            float sv[4];
#pragma unroll
            for (int j = 0; j < 4; ++j)
                sv[j] = (kbase + kk + 16 * j <= qrow[r]) ? s[r][j] : -1e30f;
            float pmax = fmaxf(fmaxf(sv[0], sv[1]), fmaxf(sv[2], sv[3]));
            pmax = fmaxf(pmax, __shfl_xor(pmax, 1));
            pmax = fmaxf(pmax, __shfl_xor(pmax, 2));
            pmax = fmaxf(pmax, __shfl_xor(pmax, 4));
            pmax = fmaxf(pmax, __shfl_xor(pmax, 8));
            const float mnew = fmaxf(m[r], pmax);
            const float fac  = __expf(m[r] - mnew);
            float psum = 0.f;
#pragma unroll
            for (int j = 0; j < 4; ++j) {
                pv[r][j] = __expf(sv[j] - mnew);
                psum += pv[r][j];
            }
            psum += __shfl_xor(psum, 1);
            psum += __shfl_xor(psum, 2);
            psum += __shfl_xor(psum, 4);
            psum += __shfl_xor(psum, 8);
            l[r] = l[r] * fac + psum;
            m[r] = mnew;
#pragma unroll
            for (int c = 0; c < 4; ++c) {
                po[r][c].x *= fac; po[r][c].y *= fac;
                po[r][c].z *= fac; po[r][c].w *= fac;
            }
        }

        // ---- PV with in-register pv ----
#pragma unroll
        for (int j = 0; j < 4; ++j) {
            const int krow = (kk + 16 * j) * 64;
            float4 vf[4];
#pragma unroll
            for (int q = 0; q < 4; ++q)
                vf[q] = *(const float4*)&Vs[krow + ((dg * 4 + q) ^ sw) * 4];
#pragma unroll
            for (int r = 0; r < 4; ++r) {
                const float p = pv[r][j];
#pragma unroll
                for (int q = 0; q < 4; ++q) {
                    po[r][q].x += p * vf[q].x; po[r][q].y += p * vf[q].y;
                    po[r][q].z += p * vf[q].z; po[r][q].w += p * vf[q].w;
                }
            }
        }
    }

    // ---- reduce po across the 16 kk lanes; write partial ----
#pragma unroll
    for (int r = 0; r < 4; ++r)
#pragma unroll
        for (int q = 0; q < 4; ++q) {
            float4 v = po[r][q];
#pragma unroll
            for (int off = 1; off < 16; off <<= 1) {
                v.x += __shfl_xor(v.x, off);
                v.y += __shfl_xor(v.y, off);
                v.z += __shfl_xor(v.z, off);
                v.w += __shfl_xor(v.w, off);
            }
            po[r][q] = v;
        }

    float* out_p = PT + (size_t)id * 1056;
    if (kk == 0) {
#pragma unroll
        for (int r = 0; r < 4; ++r)
#pragma unroll
            for (int q = 0; q < 4; ++q)
                *(float4*)&out_p[(4 * w + r) * 64 + dg * 16 + q * 4] = po[r][q];
    }
    if (lane == 0) {
#pragma unroll
        for (int r = 0; r < 4; ++r) {
            out_p[1024 + 4 * w + r] = m[r];
            out_p[1040 + 4 * w + r] = l[r];
        }
    }
}

// ---------------------------------------------------------------------------
__global__ __launch_bounds__(256)
void attn_combine(const float* __restrict__ PT, float* __restrict__ out)
{
    const int bid  = blockIdx.x;        // 0..511
    const int b    = bid >> 7;
    const int qt16 = bid & 127;
    const int G    = qt16 >> 5, rg = qt16 & 31;
    const int S    = qt16 + 16 * G * (G - 1) + rg * G;
    const int base = b * 320 + S;
    const int np   = G + 1;

    const int tid = threadIdx.x;
    const int row = tid >> 4;
    const int c4  = (tid & 15) * 4;

    float M = -1e30f;
    for (int p = 0; p < np; ++p)
        M = fmaxf(M, PT[(size_t)(base + p) * 1056 + 1024 + row]);

    float4 acc = make_float4(0.f, 0.f, 0.f, 0.f);
    float L = 0.f;
    for (int p = 0; p < np; ++p) {
        const float* q = &PT[(size_t)(base + p) * 1056];
        const float wgt = __expf(q[1024 + row] - M);
        L += wgt * q[1040 + row];
        float4 v = *(const float4*)&q[row * 64 + c4];
        acc.x += wgt * v.x; acc.y += wgt * v.y;
        acc.z += wgt * v.z; acc.w += wgt * v.w;
    }
    const float inv = 1.f / L;
    float4 o = make_float4(acc.x * inv, acc.y * inv, acc.z * inv, acc.w * inv);
    *(float4*)&out[((size_t)(b * SEQ + qt16 * 16 + row)) * HEAD + c4] = o;
}

// ---------------------------------------------------------------------------

extern "C" void kernel_launch(void* const* d_in, const int* in_sizes, int n_in,
                              void* d_out, int out_size, void* d_ws, size_t ws_size,
                              hipStream_t stream)
{
    // setup_inputs order: x, Wk, Wq, Wv
    const float* x  = (const float*)d_in[0];
    const float* Wk = (const float*)d_in[1];
    const float* Wq = (const float*)d_in[2];
    const float* Wv = (const float*)d_in[3];

    char* ws = (char*)d_ws;
    float*  P   = (float*)ws;                    // 3*8192*64*4 = 6,291,456 B
    ushort* Whl = (ushort*)(ws + 6291456);       // 2*192*1024*2 = 786,432 B
    float*  PT  = (float*)(ws + 7077888);        // 1280*1056*4 = 5,406,720 B

    prep_w      <<<dim3(192),  256, 0, stream>>>(Wq, Wk, Wv, Whl);
    qkv_mfma    <<<dim3(256),  512, 0, stream>>>(x, Whl, P);
    attn_partial<<<dim3(1280), 256, 0, stream>>>(P, PT);
    attn_combine<<<dim3(512),  256, 0, stream>>>(PT, (float*)d_out);
}

// Round 7
// 97.844 us; speedup vs baseline: 4.1405x; 3.0435x over previous
//
#include <hip/hip_runtime.h>
#include <math.h>

#define EMBED 1024
#define SEQ   2048
#define HEAD  64
#define NROW  8192   /* BATCH*SEQ */

// ---------------------------------------------------------------------------
// Round 7:
//  K0 prep_w:    (unchanged) W f32 -> Whi/Wlo bf16 [Q;K;V] rows.
//  K1 qkv_mfma:  (unchanged) split-bf16 MFMA GEMM -> P = [Q;K;V] f32.
//  K2 repack:    K f32 -> Kh/Kl bf16 (hi/lo split); V f32 -> Vt bf16 [b][d][t].
//  K3 attn_mfma: MFMA flash attention. 2 waves x 16q, 64-key swizzled LDS
//                tiles. Swapped QK^T (mfma(K,Q) = S^T) -> lane-local softmax;
//                P -> swizzled LDS -> PV A-frag; fac col->row via bpermute.
//                Uniform items (qb32, <=8-tile chunk) -> 640 blocks.
//  K4 attn_combine: merge <=4 partials (bf16 po + f32 m/l), normalize.
// ws: P 6.29MB | Whl 0.79 | Kh 1.0 | Kl 1.0 | Vt 1.0 ; PO (2.79MB) aliases
// the K/V f32 region (safe: repack runs before attn). Total 10.2MB.
// ---------------------------------------------------------------------------

typedef float f32x4  __attribute__((ext_vector_type(4)));
typedef short bf16x8 __attribute__((ext_vector_type(8)));

__device__ __forceinline__ ushort f2bf(float v) {
    union { float f; unsigned u; } t; t.f = v;
    unsigned r = t.u + 0x7FFFu + ((t.u >> 16) & 1u);   // RNE
    return (ushort)(r >> 16);
}
__device__ __forceinline__ float bf2f(ushort h) {
    union { float f; unsigned u; } t; t.u = ((unsigned)h) << 16;
    return t.f;
}

// ---------------------------------------------------------------------------
__global__ __launch_bounds__(256)
void prep_w(const float* __restrict__ Wq, const float* __restrict__ Wk,
            const float* __restrict__ Wv, ushort* __restrict__ Whl)
{
    const int idx = blockIdx.x * 256 + threadIdx.x;   // f4 index, 49152 total
    const int row = idx >> 8;                         // 0..191
    const int c4  = (idx & 255) * 4;
    const float* W = (row < 64) ? Wq : (row < 128) ? Wk : Wv;
    float4 v = *(const float4*)&W[(size_t)(row & 63) * EMBED + c4];
    float f[4] = {v.x, v.y, v.z, v.w};
    ushort h[4], l[4];
#pragma unroll
    for (int i = 0; i < 4; ++i) {
        h[i] = f2bf(f[i]);
        l[i] = f2bf(f[i] - bf2f(h[i]));
    }
    *(ushort4*)&Whl[(size_t)row * EMBED + c4]         = make_ushort4(h[0], h[1], h[2], h[3]);
    *(ushort4*)&Whl[(size_t)(192 + row) * EMBED + c4] = make_ushort4(l[0], l[1], l[2], l[3]);
}

// ---------------------------------------------------------------------------
// qkv via MFMA (unchanged from round 6 — verified working).
// ---------------------------------------------------------------------------
__global__ __launch_bounds__(512)
void qkv_mfma(const float* __restrict__ x,
              const ushort* __restrict__ Whl,
              float* __restrict__ P)
{
    __shared__ ushort Ah[2][32][40];
    __shared__ ushort Al[2][32][40];
    __shared__ ushort Bh[2][192][40];
    __shared__ ushort Bl[2][192][40];

    const int tid  = threadIdx.x;
    const int w    = tid >> 6;
    const int lane = tid & 63;
    const int kg   = w >> 2;
    const int wq   = w & 3;
    const int l15  = lane & 15, l4 = lane >> 4;
    const int row0 = blockIdx.x * 32;

    const int arow = tid >> 4;
    const int aq   = tid & 15;
    const int ag   = aq >> 3, akq = aq & 7;

    f32x4 acc[2][3];
#pragma unroll
    for (int i = 0; i < 2; ++i)
#pragma unroll
        for (int j = 0; j < 3; ++j) acc[i][j] = (f32x4){0.f, 0.f, 0.f, 0.f};

    float4 xg;
    uint4  wg[6];
    int brow[6], bkq[6], bhl[6], bg[6];
#pragma unroll
    for (int s = 0; s < 6; ++s) {
        const int u = tid + 512 * s;
        brow[s] = u >> 4;
        const int q = u & 15;
        bkq[s] = q & 3; bhl[s] = (q >> 2) & 1; bg[s] = q >> 3;
    }

    xg = *(const float4*)&x[(size_t)(row0 + arow) * EMBED + ag * 512 + akq * 4];
#pragma unroll
    for (int s = 0; s < 6; ++s)
        wg[s] = *(const uint4*)&Whl[(size_t)(bhl[s] * 192 + brow[s]) * EMBED
                                    + bg[s] * 512 + bkq[s] * 8];
    {
        float f[4] = {xg.x, xg.y, xg.z, xg.w};
        ushort h[4], l[4];
#pragma unroll
        for (int i = 0; i < 4; ++i) { h[i] = f2bf(f[i]); l[i] = f2bf(f[i] - bf2f(h[i])); }
        *(ushort4*)&Ah[ag][arow][akq * 4] = make_ushort4(h[0], h[1], h[2], h[3]);
        *(ushort4*)&Al[ag][arow][akq * 4] = make_ushort4(l[0], l[1], l[2], l[3]);
#pragma unroll
        for (int s = 0; s < 6; ++s) {
            ushort* dst = bhl[s] ? &Bl[bg[s]][brow[s]][bkq[s] * 8]
                                 : &Bh[bg[s]][brow[s]][bkq[s] * 8];
            *(uint4*)dst = wg[s];
        }
    }
    __syncthreads();

    for (int c = 0; c < 16; ++c) {
        if (c + 1 < 16) {
            const int k0 = (c + 1) * 32;
            xg = *(const float4*)&x[(size_t)(row0 + arow) * EMBED + ag * 512 + k0 + akq * 4];
#pragma unroll
            for (int s = 0; s < 6; ++s)
                wg[s] = *(const uint4*)&Whl[(size_t)(bhl[s] * 192 + brow[s]) * EMBED
                                            + bg[s] * 512 + k0 + bkq[s] * 8];
        }
        {
            const int ko = 8 * l4;
            bf16x8 ah[2], alv[2], bhv[3], blv[3];
#pragma unroll
            for (int i = 0; i < 2; ++i) {
                ah[i]  = *(const bf16x8*)&Ah[kg][16 * i + l15][ko];
                alv[i] = *(const bf16x8*)&Al[kg][16 * i + l15][ko];
            }
#pragma unroll
            for (int j = 0; j < 3; ++j) {
                bhv[j] = *(const bf16x8*)&Bh[kg][48 * wq + 16 * j + l15][ko];
                blv[j] = *(const bf16x8*)&Bl[kg][48 * wq + 16 * j + l15][ko];
            }
#pragma unroll
            for (int i = 0; i < 2; ++i)
#pragma unroll
                for (int j = 0; j < 3; ++j) {
                    acc[i][j] = __builtin_amdgcn_mfma_f32_16x16x32_bf16(ah[i],  bhv[j], acc[i][j], 0, 0, 0);
                    acc[i][j] = __builtin_amdgcn_mfma_f32_16x16x32_bf16(ah[i],  blv[j], acc[i][j], 0, 0, 0);
                    acc[i][j] = __builtin_amdgcn_mfma_f32_16x16x32_bf16(alv[i], bhv[j], acc[i][j], 0, 0, 0);
                }
        }
        __syncthreads();
        if (c + 1 < 16) {
            float f[4] = {xg.x, xg.y, xg.z, xg.w};
            ushort h[4], l[4];
#pragma unroll
            for (int i = 0; i < 4; ++i) { h[i] = f2bf(f[i]); l[i] = f2bf(f[i] - bf2f(h[i])); }
            *(ushort4*)&Ah[ag][arow][akq * 4] = make_ushort4(h[0], h[1], h[2], h[3]);
            *(ushort4*)&Al[ag][arow][akq * 4] = make_ushort4(l[0], l[1], l[2], l[3]);
#pragma unroll
            for (int s = 0; s < 6; ++s) {
                ushort* dst = bhl[s] ? &Bl[bg[s]][brow[s]][bkq[s] * 8]
                                     : &Bh[bg[s]][brow[s]][bkq[s] * 8];
                *(uint4*)dst = wg[s];
            }
        }
        __syncthreads();
    }

    __syncthreads();
    float* red = (float*)&Bh[0][0][0];
    if (kg == 1) {
#pragma unroll
        for (int i = 0; i < 2; ++i)
#pragma unroll
            for (int j = 0; j < 3; ++j)
#pragma unroll
                for (int r = 0; r < 4; ++r) {
                    const int rr = 16 * i + 4 * l4 + r;
                    const int cc = 48 * wq + 16 * j + l15;
                    red[rr * 192 + cc] = acc[i][j][r];
                }
    }
    __syncthreads();
    if (kg == 0) {
#pragma unroll
        for (int i = 0; i < 2; ++i)
#pragma unroll
            for (int j = 0; j < 3; ++j)
#pragma unroll
                for (int r = 0; r < 4; ++r) {
                    const int rr = 16 * i + 4 * l4 + r;
                    const int cc = 48 * wq + 16 * j + l15;
                    const float v = acc[i][j][r] + red[rr * 192 + cc];
                    const int which = cc >> 6, hh = cc & 63;
                    P[((size_t)which * NROW + row0 + rr) * HEAD + hh] = v;
                }
    }
}

// ---------------------------------------------------------------------------
// repack: blocks 0..511: K f32 -> Kh/Kl bf16. blocks 512..543: V -> Vt [d][t].
// ---------------------------------------------------------------------------
__global__ __launch_bounds__(256)
void repack(const float* __restrict__ P,
            ushort* __restrict__ Kh, ushort* __restrict__ Kl,
            ushort* __restrict__ Vt)
{
    const int bid = blockIdx.x;
    const int tid = threadIdx.x;
    if (bid < 512) {
        const int idx = bid * 256 + tid;              // f4 index, 131072 total
        const float4 v = *(const float4*)&P[(size_t)NROW * HEAD + (size_t)idx * 4];
        float f[4] = {v.x, v.y, v.z, v.w};
        ushort h[4], l[4];
#pragma unroll
        for (int i = 0; i < 4; ++i) {
            h[i] = f2bf(f[i]);
            l[i] = f2bf(f[i] - bf2f(h[i]));
        }
        *(ushort4*)&Kh[(size_t)idx * 4] = make_ushort4(h[0], h[1], h[2], h[3]);
        *(ushort4*)&Kl[(size_t)idx * 4] = make_ushort4(l[0], l[1], l[2], l[3]);
    } else {
        __shared__ ushort T[64][264];
        const int s  = bid - 512;                     // 0..31
        const int b  = s >> 3;
        const int k0 = (s & 7) * 256;
        const float* V = P + (size_t)2 * NROW * HEAD;
#pragma unroll
        for (int i = 0; i < 16; ++i) {
            const int u   = tid + 256 * i;            // 0..4095
            const int row = u >> 4;                   // key 0..255
            const int c4  = u & 15;
            float4 v = *(const float4*)&V[((size_t)(b * SEQ + k0 + row)) * HEAD + c4 * 4];
            T[4 * c4 + 0][row] = f2bf(v.x);
            T[4 * c4 + 1][row] = f2bf(v.y);
            T[4 * c4 + 2][row] = f2bf(v.z);
            T[4 * c4 + 3][row] = f2bf(v.w);
        }
        __syncthreads();
#pragma unroll
        for (int i = 0; i < 8; ++i) {
            const int u  = tid + 256 * i;             // 0..2047
            const int d  = u >> 5;
            const int c8 = u & 31;
            uint4 val = *(const uint4*)&T[d][c8 * 8];
            *(uint4*)&Vt[((size_t)(b * 64 + d)) * SEQ + k0 + c8 * 8] = val;
        }
    }
}

// ---------------------------------------------------------------------------
// attn_mfma: item = (b, qb32, chunk of <=8 key-tiles). 128 thr = 2 waves x 16q.
// Swapped QK^T: S^T[key][q], lane(g,c): key-frag row 4g+r, q col c.
// Swizzle: byte_in_row ^= ((row&7)<<4) on all 128B-row LDS tiles.
// ---------------------------------------------------------------------------
__global__ __launch_bounds__(128)
void attn_mfma(const float* __restrict__ Pq,
               const ushort* __restrict__ Kh, const ushort* __restrict__ Kl,
               const ushort* __restrict__ Vt, char* __restrict__ PO)
{
    // ---- item decode ----
    const int id = blockIdx.x;            // 0..639
    const int b  = id / 160;
    const int f  = id - 160 * b;
    int G, u;
    if (f < 16)      { G = 0; u = f; }
    else if (f < 48) { G = 1; u = f - 16; }
    else if (f < 96) { G = 2; u = f - 48; }
    else             { G = 3; u = f - 96; }
    const int qb  = 16 * G + u / (G + 1); // q-block-of-32 within batch, 0..63
    const int kc  = u % (G + 1);
    const int q0  = qb * 32;
    const int ktd = qb >> 1;              // diagonal tile
    const int nt  = ktd + 1;
    const int t0  = kc * 8;
    const int t1  = (t0 + 8 < nt) ? t0 + 8 : nt;

    const int tid = threadIdx.x;
    const int w   = tid >> 6;             // wave 0..1
    const int lane = tid & 63;
    const int g = lane >> 4, c = lane & 15;
    const int swz = (c & 7) << 3;         // ushort-granularity XOR key

    __shared__ ushort KH[64 * 64];
    __shared__ ushort KL[64 * 64];
    __shared__ ushort VT[64 * 64];
    __shared__ ushort PS[2][16 * 64];

    // ---- Q load + 32x scale + hi/lo split (once per block) ----
    const int qrow = q0 + 16 * w + c;     // within batch
    const float* qp = Pq + ((size_t)(b * SEQ + qrow)) * HEAD;
    bf16x8 qh[2], ql[2];
#pragma unroll
    for (int ks = 0; ks < 2; ++ks) {
        float4 a0 = *(const float4*)&qp[32 * ks + 8 * g];
        float4 a1 = *(const float4*)&qp[32 * ks + 8 * g + 4];
        float vv[8] = {a0.x, a0.y, a0.z, a0.w, a1.x, a1.y, a1.z, a1.w};
#pragma unroll
        for (int i = 0; i < 8; ++i) {
            const float fq = 32.f * vv[i];
            const ushort h = f2bf(fq);
            const ushort l = f2bf(fq - bf2f(h));
            qh[ks][i] = (short)h;
            ql[ks][i] = (short)l;
        }
    }

    f32x4 o[4];
#pragma unroll
    for (int db = 0; db < 4; ++db) o[db] = (f32x4){0.f, 0.f, 0.f, 0.f};
    float m = -1e30f, lsum = 0.f;

    for (int kt = t0; kt < t1; ++kt) {
        const int kb0 = kt * 64;
        __syncthreads();
        // ---- stage K/Kl/Vt tile (swizzled) ----
#pragma unroll
        for (int i = 0; i < 4; ++i) {
            const int u2  = tid + 128 * i;            // 0..511
            const int row = u2 >> 3, c8 = u2 & 7;
            const int dst = row * 64 + ((c8 ^ (row & 7)) * 8);
            const size_t ksrc = ((size_t)(b * SEQ + kb0 + row)) * HEAD + c8 * 8;
            *(uint4*)&KH[dst] = *(const uint4*)&Kh[ksrc];
            *(uint4*)&KL[dst] = *(const uint4*)&Kl[ksrc];
            const size_t vsrc = ((size_t)(b * 64 + row)) * SEQ + kb0 + c8 * 8;
            *(uint4*)&VT[dst] = *(const uint4*)&Vt[vsrc];
        }
        __syncthreads();

        // ---- QK^T (swapped): s[kb] = S^T frag, 3-MFMA split-bf16 ----
        f32x4 s[4];
#pragma unroll
        for (int kb = 0; kb < 4; ++kb) s[kb] = (f32x4){0.f, 0.f, 0.f, 0.f};
#pragma unroll
        for (int ks = 0; ks < 2; ++ks) {
            const int co = (32 * ks + 8 * g) ^ swz;
#pragma unroll
            for (int kb = 0; kb < 4; ++kb) {
                const int row = 16 * kb + c;
                bf16x8 ah = *(const bf16x8*)&KH[row * 64 + co];
                bf16x8 al = *(const bf16x8*)&KL[row * 64 + co];
                s[kb] = __builtin_amdgcn_mfma_f32_16x16x32_bf16(ah, qh[ks], s[kb], 0, 0, 0);
                s[kb] = __builtin_amdgcn_mfma_f32_16x16x32_bf16(ah, ql[ks], s[kb], 0, 0, 0);
                s[kb] = __builtin_amdgcn_mfma_f32_16x16x32_bf16(al, qh[ks], s[kb], 0, 0, 0);
            }
        }

        // ---- causal mask (diagonal tile only) ----
        if (kt == ktd) {
#pragma unroll
            for (int kb = 0; kb < 4; ++kb)
#pragma unroll
                for (int r = 0; r < 4; ++r)
                    if (kb0 + 16 * kb + 4 * g + r > qrow) s[kb][r] = -1e30f;
        }

        // ---- online softmax (col-form: lane holds 16 keys for q = qrow) ----
        float tmax = -1e30f;
#pragma unroll
        for (int kb = 0; kb < 4; ++kb) {
            float a = fmaxf(fmaxf(s[kb][0], s[kb][1]), fmaxf(s[kb][2], s[kb][3]));
            tmax = fmaxf(tmax, a);
        }
        tmax = fmaxf(tmax, __shfl_xor(tmax, 16));
        tmax = fmaxf(tmax, __shfl_xor(tmax, 32));
        const float mnew = fmaxf(m, tmax);
        const float fac  = __expf(m - mnew);
        float p[4][4];
        float psum = 0.f;
#pragma unroll
        for (int kb = 0; kb < 4; ++kb)
#pragma unroll
            for (int r = 0; r < 4; ++r) {
                p[kb][r] = __expf(s[kb][r] - mnew);
                psum += p[kb][r];
            }
        psum += __shfl_xor(psum, 16);
        psum += __shfl_xor(psum, 32);
        lsum = lsum * fac + psum;
        m = mnew;

        // ---- fac: col-form -> row-form broadcast; rescale o ----
        float fb[4];
#pragma unroll
        for (int r = 0; r < 4; ++r) fb[r] = __shfl(fac, 4 * g + r);
#pragma unroll
        for (int db = 0; db < 4; ++db) {
            o[db][0] *= fb[0]; o[db][1] *= fb[1];
            o[db][2] *= fb[2]; o[db][3] *= fb[3];
        }

        // ---- p -> bf16 -> PS (swizzled rows of P[q][k]) ----
#pragma unroll
        for (int kb = 0; kb < 4; ++kb) {
            const int idx = c * 64 + (((16 * kb + 4 * g)) ^ swz);
            *(ushort4*)&PS[w][idx] = make_ushort4(
                f2bf(p[kb][0]), f2bf(p[kb][1]), f2bf(p[kb][2]), f2bf(p[kb][3]));
        }

        // ---- PV: o[db] += P(16q x 64k) . V(64k x 16d) ----
#pragma unroll
        for (int k2 = 0; k2 < 2; ++k2) {
            const int co = (32 * k2 + 8 * g) ^ swz;
            bf16x8 pa = *(const bf16x8*)&PS[w][c * 64 + co];
#pragma unroll
            for (int db = 0; db < 4; ++db) {
                const int row = 16 * db + c;
                bf16x8 vb = *(const bf16x8*)&VT[row * 64 + co];
                o[db] = __builtin_amdgcn_mfma_f32_16x16x32_bf16(pa, vb, o[db], 0, 0, 0);
            }
        }
    }

    // ---- write partial: po bf16 [32][64], m/l f32 [2][32] ----
    char* item = PO + (size_t)id * 4352;
    ushort* po = (ushort*)item;
    float*  ml = (float*)(item + 4096);
#pragma unroll
    for (int db = 0; db < 4; ++db)
#pragma unroll
        for (int r = 0; r < 4; ++r) {
            const int qq = 16 * w + 4 * g + r;
            po[qq * 64 + 16 * db + c] = f2bf(o[db][r]);
        }
    if (g == 0) {
        ml[16 * w + c]      = m;
        ml[32 + 16 * w + c] = lsum;
    }
}

// ---------------------------------------------------------------------------
__global__ __launch_bounds__(256)
void attn_combine(const char* __restrict__ PO, float* __restrict__ out)
{
    const int qbg = blockIdx.x;            // 0..255
    const int b   = qbg >> 6, qb = qbg & 63;
    const int G   = qb >> 4, np = G + 1;
    const int base = b * 160 + (G + 1) * (qb - 8 * G);
    const int tid = threadIdx.x;
    const int row = tid >> 3, c8 = tid & 7;

    float M = -1e30f;
    for (int p = 0; p < np; ++p) {
        const float* ml = (const float*)(PO + (size_t)(base + p) * 4352 + 4096);
        M = fmaxf(M, ml[row]);
    }
    float L = 0.f;
    float acc[8];
#pragma unroll
    for (int j = 0; j < 8; ++j) acc[j] = 0.f;
    for (int p = 0; p < np; ++p) {
        const char* item = PO + (size_t)(base + p) * 4352;
        const float* ml  = (const float*)(item + 4096);
        const float wgt  = __expf(ml[row] - M);
        L += wgt * ml[32 + row];
        const ushort* po = (const ushort*)item;
        ushort4 a0 = *(const ushort4*)&po[row * 64 + c8 * 8];
        ushort4 a1 = *(const ushort4*)&po[row * 64 + c8 * 8 + 4];
        acc[0] += wgt * bf2f(a0.x); acc[1] += wgt * bf2f(a0.y);
        acc[2] += wgt * bf2f(a0.z); acc[3] += wgt * bf2f(a0.w);
        acc[4] += wgt * bf2f(a1.x); acc[5] += wgt * bf2f(a1.y);
        acc[6] += wgt * bf2f(a1.z); acc[7] += wgt * bf2f(a1.w);
    }
    const float inv = 1.f / L;
    float* dst = &out[((size_t)(b * SEQ + qb * 32 + row)) * HEAD + c8 * 8];
    *(float4*)dst      = make_float4(acc[0] * inv, acc[1] * inv, acc[2] * inv, acc[3] * inv);
    *(float4*)(dst + 4) = make_float4(acc[4] * inv, acc[5] * inv, acc[6] * inv, acc[7] * inv);
}

// ---------------------------------------------------------------------------

extern "C" void kernel_launch(void* const* d_in, const int* in_sizes, int n_in,
                              void* d_out, int out_size, void* d_ws, size_t ws_size,
                              hipStream_t stream)
{
    // setup_inputs order: x, Wk, Wq, Wv
    const float* x  = (const float*)d_in[0];
    const float* Wk = (const float*)d_in[1];
    const float* Wq = (const float*)d_in[2];
    const float* Wv = (const float*)d_in[3];

    char* ws = (char*)d_ws;
    float*  P   = (float*)ws;                    // Q|K|V f32: 6,291,456 B
    ushort* Whl = (ushort*)(ws + 6291456);       //   786,432 B
    ushort* Kh  = (ushort*)(ws + 7077888);       // 1,048,576 B
    ushort* Kl  = (ushort*)(ws + 8126464);       // 1,048,576 B
    ushort* Vt  = (ushort*)(ws + 9175040);       // 1,048,576 B
    char*   PO  = ws + 2097152;                  // 2,785,280 B (aliases K/V f32)

    prep_w      <<<dim3(192), 256, 0, stream>>>(Wq, Wk, Wv, Whl);
    qkv_mfma    <<<dim3(256), 512, 0, stream>>>(x, Whl, P);
    repack      <<<dim3(544), 256, 0, stream>>>(P, Kh, Kl, Vt);
    attn_mfma   <<<dim3(640), 128, 0, stream>>>(P, Kh, Kl, Vt, PO);
    attn_combine<<<dim3(256), 256, 0, stream>>>(PO, (float*)d_out);
}

// Round 8
// 92.986 us; speedup vs baseline: 4.3569x; 1.0522x over previous
//
#include <hip/hip_runtime.h>
#include <math.h>

#define EMBED 1024
#define SEQ   2048
#define HEAD  64
#define NROW  8192   /* BATCH*SEQ */

// ---------------------------------------------------------------------------
// Round 8:
//  K0 prep_w:   W f32 -> Wt, tiled in MFMA-slice order: 16 k-chunks x 40
//               slices x 64 lanes x 8 bf16. Slices: Q/K split hi+lo, V hi only.
//  K1 qkv_mfma<RF,KSP>: BM=RF*16 rows x 192 cols, K split KSP-ways across
//               blocks (512 blocks either way -> 2 blocks/CU). Fragment-major
//               LDS (lane*16B contiguous reads AND writes -> conflict-free).
//               V un-split (1 MFMA), Q/K split (3 MFMAs), frags {w,w+4,w+8}
//               per wave for balance.
//  K2 reduce_repack<H>: merge K-split halves; Q -> 32x-scaled split Qh/Ql bf16;
//               K -> Kh/Kl bf16; V -> Vt bf16 [b][d][t].
//  K3 attn_mfma: (round-7 structure, verified) now loads pre-split Qh/Ql.
//  K4 attn_combine: unchanged.
// ws (big path, 18.5MB): P2 12.58 | Wt 0.66 | Qh,Ql,Kh,Kl,Vt 5.24; PO aliases
// P2 (dead after reduce_repack). Fallback (<18.5MB ws): full-K BM=16, 12.2MB.
// ---------------------------------------------------------------------------

typedef float f32x4  __attribute__((ext_vector_type(4)));
typedef short bf16x8 __attribute__((ext_vector_type(8)));

__device__ __forceinline__ ushort f2bf(float v) {
    union { float f; unsigned u; } t; t.f = v;
    unsigned r = t.u + 0x7FFFu + ((t.u >> 16) & 1u);   // RNE
    return (ushort)(r >> 16);
}
__device__ __forceinline__ float bf2f(ushort h) {
    union { float f; unsigned u; } t; t.u = ((unsigned)h) << 16;
    return t.f;
}
__device__ __forceinline__ uint4 pack8(const ushort* o) {
    uint4 u;
    u.x = (unsigned)o[0] | ((unsigned)o[1] << 16);
    u.y = (unsigned)o[2] | ((unsigned)o[3] << 16);
    u.z = (unsigned)o[4] | ((unsigned)o[5] << 16);
    u.w = (unsigned)o[6] | ((unsigned)o[7] << 16);
    return u;
}

// ---------------------------------------------------------------------------
// prep_w: cell id -> (g,s,l). s<32: f=s>>2 (Q:0-3,K:4-7), hl=(s>>1)&1, ks=s&1;
// s>=32: f=8+((s-32)>>1) (V), hl=0, ks=(s-32)&1.
// element = split( W[col=(f&3)*16+(l&15)] [k = g*64+ks*32+(l>>4)*8 + 0..8) )
// ---------------------------------------------------------------------------
__global__ __launch_bounds__(256)
void prep_w(const float* __restrict__ Wq, const float* __restrict__ Wk,
            const float* __restrict__ Wv, ushort* __restrict__ Wt)
{
    const int id = blockIdx.x * 256 + threadIdx.x;   // 0..40959
    const int g  = id / 2560;
    const int r1 = id - g * 2560;
    const int s  = r1 >> 6, l = r1 & 63;
    int f, hl, ks;
    if (s < 32) { f = s >> 2; hl = (s >> 1) & 1; ks = s & 1; }
    else        { int t = s - 32; f = 8 + (t >> 1); hl = 0; ks = t & 1; }
    const float* W = (f < 4) ? Wq : (f < 8) ? Wk : Wv;
    const int col = (f & 3) * 16 + (l & 15);
    const int k   = g * 64 + ks * 32 + (l >> 4) * 8;
    float4 v0 = *(const float4*)&W[(size_t)col * EMBED + k];
    float4 v1 = *(const float4*)&W[(size_t)col * EMBED + k + 4];
    const float vv[8] = {v0.x, v0.y, v0.z, v0.w, v1.x, v1.y, v1.z, v1.w};
    ushort o[8];
#pragma unroll
    for (int i = 0; i < 8; ++i) {
        const ushort h = f2bf(vv[i]);
        o[i] = hl ? f2bf(vv[i] - bf2f(h)) : h;
    }
    *(uint4*)&Wt[((size_t)g * 40 + s) * 512 + l * 8] = pack8(o);
}

// ---------------------------------------------------------------------------
// qkv GEMM. 256 thr = 4 waves; wave w owns frags {w (Q), w+4 (K), w+8 (V)},
// all BM rows. LDS slice = 1KB; read/write addr = slicebase + lane*16B.
// ---------------------------------------------------------------------------
template<int RF, int KSP>
__global__ __launch_bounds__(256)
void qkv_mfma_t(const float* __restrict__ x, const ushort* __restrict__ Wt,
                float* __restrict__ P2)
{
    constexpr int BM = RF * 16;
    constexpr int CH = 1024 / (KSP * 64);
    __shared__ ushort SA[RF * 4 * 512];
    __shared__ ushort SB[40 * 512];

    const int tid  = threadIdx.x;
    const int w    = tid >> 6;
    const int lane = tid & 63;
    const int bid  = blockIdx.x;
    const int kz   = (KSP == 1) ? 0 : (bid & 1);
    const int mt   = (KSP == 1) ? bid : (bid >> 1);
    const int row0 = mt * BM;
    const int g0   = kz * CH;

    f32x4 acc[RF][3];
#pragma unroll
    for (int rf = 0; rf < RF; ++rf)
#pragma unroll
        for (int fi = 0; fi < 3; ++fi) acc[rf][fi] = (f32x4){0.f, 0.f, 0.f, 0.f};

    // staging identities
    const int  xrow = tid >> 3;       // 0..31
    const int  xk   = tid & 7;        // k-cell (8 bf16) within BK=64
    const bool xact = (xrow < BM);
    uint4  wreg[10];
    float4 xa, xb;

    // ---- prologue: load + commit chunk 0 ----
    {
        const int g = g0;
#pragma unroll
        for (int i = 0; i < 10; ++i) {
            const int cell = tid + 256 * i, s = cell >> 6, l = cell & 63;
            wreg[i] = *(const uint4*)&Wt[((size_t)g * 40 + s) * 512 + l * 8];
        }
        if (xact) {
            const float* xp = &x[(size_t)(row0 + xrow) * EMBED + g * 64 + xk * 8];
            xa = *(const float4*)xp; xb = *(const float4*)(xp + 4);
        }
#pragma unroll
        for (int i = 0; i < 10; ++i) {
            const int cell = tid + 256 * i, s = cell >> 6, l = cell & 63;
            *(uint4*)&SB[s * 512 + l * 8] = wreg[i];
        }
        if (xact) {
            const float vv[8] = {xa.x, xa.y, xa.z, xa.w, xb.x, xb.y, xb.z, xb.w};
            ushort hs[8], ls[8];
#pragma unroll
            for (int i = 0; i < 8; ++i) {
                hs[i] = f2bf(vv[i]); ls[i] = f2bf(vv[i] - bf2f(hs[i]));
            }
            const int rf = xrow >> 4, rowin = xrow & 15, ks = xk >> 2, oc = xk & 3;
            const int base = ((rf * 2) * 2 + ks) * 512 + oc * 128 + rowin * 8;
            *(uint4*)&SA[base]        = pack8(hs);
            *(uint4*)&SA[base + 1024] = pack8(ls);   // hl=1 -> +2 slices
        }
    }
    __syncthreads();

    for (int c = 0; c < CH; ++c) {
        // ---- issue next chunk's global loads ----
        if (c + 1 < CH) {
            const int g = g0 + c + 1;
#pragma unroll
            for (int i = 0; i < 10; ++i) {
                const int cell = tid + 256 * i, s = cell >> 6, l = cell & 63;
                wreg[i] = *(const uint4*)&Wt[((size_t)g * 40 + s) * 512 + l * 8];
            }
            if (xact) {
                const float* xp = &x[(size_t)(row0 + xrow) * EMBED + g * 64 + xk * 8];
                xa = *(const float4*)xp; xb = *(const float4*)(xp + 4);
            }
        }
        // ---- MFMA on current buffer ----
#pragma unroll
        for (int ks = 0; ks < 2; ++ks) {
            bf16x8 ah[RF], al[RF];
#pragma unroll
            for (int rf = 0; rf < RF; ++rf) {
                ah[rf] = *(const bf16x8*)&SA[((rf * 2 + 0) * 2 + ks) * 512 + lane * 8];
                al[rf] = *(const bf16x8*)&SA[((rf * 2 + 1) * 2 + ks) * 512 + lane * 8];
            }
#pragma unroll
            for (int fi = 0; fi < 2; ++fi) {              // Q, K frags: split
                const int f = w + 4 * fi;
                bf16x8 bh = *(const bf16x8*)&SB[(f * 4 + ks) * 512 + lane * 8];
                bf16x8 bl = *(const bf16x8*)&SB[(f * 4 + 2 + ks) * 512 + lane * 8];
#pragma unroll
                for (int rf = 0; rf < RF; ++rf) {
                    acc[rf][fi] = __builtin_amdgcn_mfma_f32_16x16x32_bf16(ah[rf], bh, acc[rf][fi], 0, 0, 0);
                    acc[rf][fi] = __builtin_amdgcn_mfma_f32_16x16x32_bf16(ah[rf], bl, acc[rf][fi], 0, 0, 0);
                    acc[rf][fi] = __builtin_amdgcn_mfma_f32_16x16x32_bf16(al[rf], bh, acc[rf][fi], 0, 0, 0);
                }
            }
            {                                              // V frag: hi only
                bf16x8 bv = *(const bf16x8*)&SB[(32 + w * 2 + ks) * 512 + lane * 8];
#pragma unroll
                for (int rf = 0; rf < RF; ++rf)
                    acc[rf][2] = __builtin_amdgcn_mfma_f32_16x16x32_bf16(ah[rf], bv, acc[rf][2], 0, 0, 0);
            }
        }
        __syncthreads();
        // ---- commit staged regs ----
        if (c + 1 < CH) {
#pragma unroll
            for (int i = 0; i < 10; ++i) {
                const int cell = tid + 256 * i, s = cell >> 6, l = cell & 63;
                *(uint4*)&SB[s * 512 + l * 8] = wreg[i];
            }
            if (xact) {
                const float vv[8] = {xa.x, xa.y, xa.z, xa.w, xb.x, xb.y, xb.z, xb.w};
                ushort hs[8], ls[8];
#pragma unroll
                for (int i = 0; i < 8; ++i) {
                    hs[i] = f2bf(vv[i]); ls[i] = f2bf(vv[i] - bf2f(hs[i]));
                }
                const int rf = xrow >> 4, rowin = xrow & 15, ks = xk >> 2, oc = xk & 3;
                const int base = ((rf * 2) * 2 + ks) * 512 + oc * 128 + rowin * 8;
                *(uint4*)&SA[base]        = pack8(hs);
                *(uint4*)&SA[base + 1024] = pack8(ls);
            }
        }
        __syncthreads();
    }

    // ---- epilogue: partial P (f32). D: row=(l>>4)*4+r, col=l&15 ----
    float* Pout = P2 + (size_t)kz * 3 * NROW * HEAD;
#pragma unroll
    for (int rf = 0; rf < RF; ++rf)
#pragma unroll
        for (int fi = 0; fi < 3; ++fi) {
            const int f     = w + 4 * fi;
            const int which = f >> 2;
            const int colw  = (f & 3) * 16 + (lane & 15);
#pragma unroll
            for (int r = 0; r < 4; ++r) {
                const int row = row0 + rf * 16 + (lane >> 4) * 4 + r;
                Pout[((size_t)which * NROW + row) * HEAD + colw] = acc[rf][fi][r];
            }
        }
}

// ---------------------------------------------------------------------------
// reduce_repack: bid<512: elementwise Q (x32, split) / K (split);
// bid 512..543: V transpose -> Vt bf16 [b][d][t]. H: sum K-split halves.
// ---------------------------------------------------------------------------
template<bool H>
__global__ __launch_bounds__(256)
void reduce_repack(const float* __restrict__ P2,
                   ushort* __restrict__ Qh, ushort* __restrict__ Ql,
                   ushort* __restrict__ Kh, ushort* __restrict__ Kl,
                   ushort* __restrict__ Vt)
{
    const size_t HS  = (size_t)3 * NROW * HEAD;
    const int bid = blockIdx.x, tid = threadIdx.x;
    if (bid < 512) {
        const int which = bid >> 8;
        ushort* Oh = which ? Kh : Qh;
        ushort* Ol = which ? Kl : Ql;
        const float sc = which ? 1.f : 32.f;
        const float* B0 = P2 + (size_t)which * NROW * HEAD;
#pragma unroll
        for (int j = 0; j < 2; ++j) {
            const int fidx = (bid & 255) * 512 + j * 256 + tid;
            float4 a = *(const float4*)&B0[(size_t)fidx * 4];
            if (H) {
                float4 b2 = *(const float4*)&B0[HS + (size_t)fidx * 4];
                a.x += b2.x; a.y += b2.y; a.z += b2.z; a.w += b2.w;
            }
            const float vv[4] = {sc * a.x, sc * a.y, sc * a.z, sc * a.w};
            ushort h[4], l[4];
#pragma unroll
            for (int i = 0; i < 4; ++i) {
                h[i] = f2bf(vv[i]); l[i] = f2bf(vv[i] - bf2f(h[i]));
            }
            *(ushort4*)&Oh[(size_t)fidx * 4] = make_ushort4(h[0], h[1], h[2], h[3]);
            *(ushort4*)&Ol[(size_t)fidx * 4] = make_ushort4(l[0], l[1], l[2], l[3]);
        }
    } else {
        __shared__ ushort T[64][264];
        const int s  = bid - 512;                 // 0..31
        const int b  = s >> 3;
        const int k0 = (s & 7) * 256;
        const float* V0 = P2 + (size_t)2 * NROW * HEAD;
#pragma unroll
        for (int i = 0; i < 16; ++i) {
            const int u = tid + 256 * i;          // 0..4095
            const int row = u >> 4, c4 = u & 15;
            const size_t gi = ((size_t)(b * SEQ + k0 + row)) * HEAD + c4 * 4;
            float4 v = *(const float4*)&V0[gi];
            if (H) {
                float4 v1 = *(const float4*)&V0[HS + gi];
                v.x += v1.x; v.y += v1.y; v.z += v1.z; v.w += v1.w;
            }
            T[4 * c4 + 0][row] = f2bf(v.x);
            T[4 * c4 + 1][row] = f2bf(v.y);
            T[4 * c4 + 2][row] = f2bf(v.z);
            T[4 * c4 + 3][row] = f2bf(v.w);
        }
        __syncthreads();
#pragma unroll
        for (int i = 0; i < 8; ++i) {
            const int u = tid + 256 * i;          // 0..2047
            const int d = u >> 5, c8 = u & 31;
            uint4 val = *(const uint4*)&T[d][c8 * 8];
            *(uint4*)&Vt[((size_t)(b * 64 + d)) * SEQ + k0 + c8 * 8] = val;
        }
    }
}

// ---------------------------------------------------------------------------
// attn_mfma (round-7 verified structure): 2 waves x 16q, 64-key swizzled LDS
// tiles; swapped QK^T -> lane-local softmax; P via swizzled LDS to PV A-frag.
// Q now pre-split bf16 (scale folded).
// ---------------------------------------------------------------------------
__global__ __launch_bounds__(128)
void attn_mfma(const ushort* __restrict__ Qh, const ushort* __restrict__ Ql,
               const ushort* __restrict__ Kh, const ushort* __restrict__ Kl,
               const ushort* __restrict__ Vt, char* __restrict__ PO)
{
    const int id = blockIdx.x;            // 0..639
    const int b  = id / 160;
    const int f  = id - 160 * b;
    int G, u;
    if (f < 16)      { G = 0; u = f; }
    else if (f < 48) { G = 1; u = f - 16; }
    else if (f < 96) { G = 2; u = f - 48; }
    else             { G = 3; u = f - 96; }
    const int qb  = 16 * G + u / (G + 1);
    const int kc  = u % (G + 1);
    const int q0  = qb * 32;
    const int ktd = qb >> 1;
    const int nt  = ktd + 1;
    const int t0  = kc * 8;
    const int t1  = (t0 + 8 < nt) ? t0 + 8 : nt;

    const int tid = threadIdx.x;
    const int w   = tid >> 6;
    const int lane = tid & 63;
    const int g = lane >> 4, c = lane & 15;
    const int swz = (c & 7) << 3;

    __shared__ ushort KH[64 * 64];
    __shared__ ushort KL[64 * 64];
    __shared__ ushort VT[64 * 64];
    __shared__ ushort PS[2][16 * 64];

    // ---- Q frags: pre-split bf16, scale already folded ----
    const int qrow = q0 + 16 * w + c;
    bf16x8 qh[2], ql[2];
#pragma unroll
    for (int ks = 0; ks < 2; ++ks) {
        const size_t qi = ((size_t)(b * SEQ + qrow)) * HEAD + 32 * ks + 8 * g;
        qh[ks] = *(const bf16x8*)&Qh[qi];
        ql[ks] = *(const bf16x8*)&Ql[qi];
    }

    f32x4 o[4];
#pragma unroll
    for (int db = 0; db < 4; ++db) o[db] = (f32x4){0.f, 0.f, 0.f, 0.f};
    float m = -1e30f, lsum = 0.f;

    for (int kt = t0; kt < t1; ++kt) {
        const int kb0 = kt * 64;
        __syncthreads();
#pragma unroll
        for (int i = 0; i < 4; ++i) {
            const int u2  = tid + 128 * i;
            const int row = u2 >> 3, c8 = u2 & 7;
            const int dst = row * 64 + ((c8 ^ (row & 7)) * 8);
            const size_t ksrc = ((size_t)(b * SEQ + kb0 + row)) * HEAD + c8 * 8;
            *(uint4*)&KH[dst] = *(const uint4*)&Kh[ksrc];
            *(uint4*)&KL[dst] = *(const uint4*)&Kl[ksrc];
            const size_t vsrc = ((size_t)(b * 64 + row)) * SEQ + kb0 + c8 * 8;
            *(uint4*)&VT[dst] = *(const uint4*)&Vt[vsrc];
        }
        __syncthreads();

        f32x4 s[4];
#pragma unroll
        for (int kb = 0; kb < 4; ++kb) s[kb] = (f32x4){0.f, 0.f, 0.f, 0.f};
#pragma unroll
        for (int ks = 0; ks < 2; ++ks) {
            const int co = (32 * ks + 8 * g) ^ swz;
#pragma unroll
            for (int kb = 0; kb < 4; ++kb) {
                const int row = 16 * kb + c;
                bf16x8 ah = *(const bf16x8*)&KH[row * 64 + co];
                bf16x8 al = *(const bf16x8*)&KL[row * 64 + co];
                s[kb] = __builtin_amdgcn_mfma_f32_16x16x32_bf16(ah, qh[ks], s[kb], 0, 0, 0);
                s[kb] = __builtin_amdgcn_mfma_f32_16x16x32_bf16(ah, ql[ks], s[kb], 0, 0, 0);
                s[kb] = __builtin_amdgcn_mfma_f32_16x16x32_bf16(al, qh[ks], s[kb], 0, 0, 0);
            }
        }

        if (kt == ktd) {
#pragma unroll
            for (int kb = 0; kb < 4; ++kb)
#pragma unroll
                for (int r = 0; r < 4; ++r)
                    if (kb0 + 16 * kb + 4 * g + r > qrow) s[kb][r] = -1e30f;
        }

        float tmax = -1e30f;
#pragma unroll
        for (int kb = 0; kb < 4; ++kb) {
            float a = fmaxf(fmaxf(s[kb][0], s[kb][1]), fmaxf(s[kb][2], s[kb][3]));
            tmax = fmaxf(tmax, a);
        }
        tmax = fmaxf(tmax, __shfl_xor(tmax, 16));
        tmax = fmaxf(tmax, __shfl_xor(tmax, 32));
        const float mnew = fmaxf(m, tmax);
        const float fac  = __expf(m - mnew);
        float p[4][4];
        float psum = 0.f;
#pragma unroll
        for (int kb = 0; kb < 4; ++kb)
#pragma unroll
            for (int r = 0; r < 4; ++r) {
                p[kb][r] = __expf(s[kb][r] - mnew);
                psum += p[kb][r];
            }
        psum += __shfl_xor(psum, 16);
        psum += __shfl_xor(psum, 32);
        lsum = lsum * fac + psum;
        m = mnew;

        float fb[4];
#pragma unroll
        for (int r = 0; r < 4; ++r) fb[r] = __shfl(fac, 4 * g + r);
#pragma unroll
        for (int db = 0; db < 4; ++db) {
            o[db][0] *= fb[0]; o[db][1] *= fb[1];
            o[db][2] *= fb[2]; o[db][3] *= fb[3];
        }

#pragma unroll
        for (int kb = 0; kb < 4; ++kb) {
            const int idx = c * 64 + (((16 * kb + 4 * g)) ^ swz);
            *(ushort4*)&PS[w][idx] = make_ushort4(
                f2bf(p[kb][0]), f2bf(p[kb][1]), f2bf(p[kb][2]), f2bf(p[kb][3]));
        }

#pragma unroll
        for (int k2 = 0; k2 < 2; ++k2) {
            const int co = (32 * k2 + 8 * g) ^ swz;
            bf16x8 pa = *(const bf16x8*)&PS[w][c * 64 + co];
#pragma unroll
            for (int db = 0; db < 4; ++db) {
                const int row = 16 * db + c;
                bf16x8 vb = *(const bf16x8*)&VT[row * 64 + co];
                o[db] = __builtin_amdgcn_mfma_f32_16x16x32_bf16(pa, vb, o[db], 0, 0, 0);
            }
        }
    }

    char* item = PO + (size_t)id * 4352;
    ushort* po = (ushort*)item;
    float*  ml = (float*)(item + 4096);
#pragma unroll
    for (int db = 0; db < 4; ++db)
#pragma unroll
        for (int r = 0; r < 4; ++r) {
            const int qq = 16 * w + 4 * g + r;
            po[qq * 64 + 16 * db + c] = f2bf(o[db][r]);
        }
    if (g == 0) {
        ml[16 * w + c]      = m;
        ml[32 + 16 * w + c] = lsum;
    }
}

// ---------------------------------------------------------------------------
__global__ __launch_bounds__(256)
void attn_combine(const char* __restrict__ PO, float* __restrict__ out)
{
    const int qbg = blockIdx.x;            // 0..255
    const int b   = qbg >> 6, qb = qbg & 63;
    const int G   = qb >> 4, np = G + 1;
    const int base = b * 160 + (G + 1) * (qb - 8 * G);
    const int tid = threadIdx.x;
    const int row = tid >> 3, c8 = tid & 7;

    float M = -1e30f;
    for (int p = 0; p < np; ++p) {
        const float* ml = (const float*)(PO + (size_t)(base + p) * 4352 + 4096);
        M = fmaxf(M, ml[row]);
    }
    float L = 0.f;
    float acc[8];
#pragma unroll
    for (int j = 0; j < 8; ++j) acc[j] = 0.f;
    for (int p = 0; p < np; ++p) {
        const char* item = PO + (size_t)(base + p) * 4352;
        const float* ml  = (const float*)(item + 4096);
        const float wgt  = __expf(ml[row] - M);
        L += wgt * ml[32 + row];
        const ushort* po = (const ushort*)item;
        ushort4 a0 = *(const ushort4*)&po[row * 64 + c8 * 8];
        ushort4 a1 = *(const ushort4*)&po[row * 64 + c8 * 8 + 4];
        acc[0] += wgt * bf2f(a0.x); acc[1] += wgt * bf2f(a0.y);
        acc[2] += wgt * bf2f(a0.z); acc[3] += wgt * bf2f(a0.w);
        acc[4] += wgt * bf2f(a1.x); acc[5] += wgt * bf2f(a1.y);
        acc[6] += wgt * bf2f(a1.z); acc[7] += wgt * bf2f(a1.w);
    }
    const float inv = 1.f / L;
    float* dst = &out[((size_t)(b * SEQ + qb * 32 + row)) * HEAD + c8 * 8];
    *(float4*)dst       = make_float4(acc[0] * inv, acc[1] * inv, acc[2] * inv, acc[3] * inv);
    *(float4*)(dst + 4) = make_float4(acc[4] * inv, acc[5] * inv, acc[6] * inv, acc[7] * inv);
}

// ---------------------------------------------------------------------------

extern "C" void kernel_launch(void* const* d_in, const int* in_sizes, int n_in,
                              void* d_out, int out_size, void* d_ws, size_t ws_size,
                              hipStream_t stream)
{
    // setup_inputs order: x, Wk, Wq, Wv
    const float* x  = (const float*)d_in[0];
    const float* Wk = (const float*)d_in[1];
    const float* Wq = (const float*)d_in[2];
    const float* Wv = (const float*)d_in[3];

    char* ws = (char*)d_ws;
    const bool big = (ws_size >= (size_t)18481152);

    // buffer layout (bytes)
    const size_t P2_SZ = big ? 12582912 : 6291456;     // f32 partials (x2 or x1)
    const size_t WT_OFF = P2_SZ;
    const size_t QH_OFF = WT_OFF + 655360;
    const size_t QL_OFF = QH_OFF + 1048576;
    const size_t KH_OFF = QL_OFF + 1048576;
    const size_t KL_OFF = KH_OFF + 1048576;
    const size_t VT_OFF = KL_OFF + 1048576;

    float*  P2  = (float*)ws;
    ushort* Wt  = (ushort*)(ws + WT_OFF);
    ushort* Qh  = (ushort*)(ws + QH_OFF);
    ushort* Ql  = (ushort*)(ws + QL_OFF);
    ushort* Kh  = (ushort*)(ws + KH_OFF);
    ushort* Kl  = (ushort*)(ws + KL_OFF);
    ushort* Vt  = (ushort*)(ws + VT_OFF);
    char*   PO  = ws;                                  // aliases P2 (dead)

    prep_w<<<dim3(160), 256, 0, stream>>>(Wq, Wk, Wv, Wt);
    if (big) {
        qkv_mfma_t<2, 2><<<dim3(512), 256, 0, stream>>>(x, Wt, P2);
        reduce_repack<true><<<dim3(544), 256, 0, stream>>>(P2, Qh, Ql, Kh, Kl, Vt);
    } else {
        qkv_mfma_t<1, 1><<<dim3(512), 256, 0, stream>>>(x, Wt, P2);
        reduce_repack<false><<<dim3(544), 256, 0, stream>>>(P2, Qh, Ql, Kh, Kl, Vt);
    }
    attn_mfma   <<<dim3(640), 128, 0, stream>>>(Qh, Ql, Kh, Kl, Vt, PO);
    attn_combine<<<dim3(256), 256, 0, stream>>>(PO, (float*)d_out);
}

// Round 9
// 92.886 us; speedup vs baseline: 4.3616x; 1.0011x over previous
//
#include <hip/hip_runtime.h>
#include <math.h>

#define EMBED 1024
#define SEQ   2048
#define HEAD  64
#define NROW  8192   /* BATCH*SEQ */

// ---------------------------------------------------------------------------
// Round 8:
//  K0 prep_w:   W f32 -> Wt, tiled in MFMA-slice order: 16 k-chunks x 40
//               slices x 64 lanes x 8 bf16. Slices: Q/K split hi+lo, V hi only.
//  K1 qkv_mfma<RF,KSP>: BM=RF*16 rows x 192 cols, K split KSP-ways across
//               blocks (512 blocks either way -> 2 blocks/CU). Fragment-major
//               LDS (lane*16B contiguous reads AND writes -> conflict-free).
//               V un-split (1 MFMA), Q/K split (3 MFMAs), frags {w,w+4,w+8}
//               per wave for balance.
//  K2 reduce_repack<H>: merge K-split halves; Q -> 32x-scaled split Qh/Ql bf16;
//               K -> Kh/Kl bf16; V -> Vt bf16 [b][d][t].
//  K3 attn_mfma: (round-7 structure, verified) now loads pre-split Qh/Ql.
//  K4 attn_combine: unchanged.
// ws (big path, 18.5MB): P2 12.58 | Wt 0.66 | Qh,Ql,Kh,Kl,Vt 5.24; PO aliases
// P2 (dead after reduce_repack). Fallback (<18.5MB ws): full-K BM=16, 12.2MB.
// ---------------------------------------------------------------------------

typedef float f32x4  __attribute__((ext_vector_type(4)));
typedef short bf16x8 __attribute__((ext_vector_type(8)));

__device__ __forceinline__ ushort f2bf(float v) {
    union { float f; unsigned u; } t; t.f = v;
    unsigned r = t.u + 0x7FFFu + ((t.u >> 16) & 1u);   // RNE
    return (ushort)(r >> 16);
}
__device__ __forceinline__ float bf2f(ushort h) {
    union { float f; unsigned u; } t; t.u = ((unsigned)h) << 16;
    return t.f;
}
__device__ __forceinline__ uint4 pack8(const ushort* o) {
    uint4 u;
    u.x = (unsigned)o[0] | ((unsigned)o[1] << 16);
    u.y = (unsigned)o[2] | ((unsigned)o[3] << 16);
    u.z = (unsigned)o[4] | ((unsigned)o[5] << 16);
    u.w = (unsigned)o[6] | ((unsigned)o[7] << 16);
    return u;
}

// ---------------------------------------------------------------------------
// prep_w: cell id -> (g,s,l). s<32: f=s>>2 (Q:0-3,K:4-7), hl=(s>>1)&1, ks=s&1;
// s>=32: f=8+((s-32)>>1) (V), hl=0, ks=(s-32)&1.
// element = split( W[col=(f&3)*16+(l&15)] [k = g*64+ks*32+(l>>4)*8 + 0..8) )
// ---------------------------------------------------------------------------
__global__ __launch_bounds__(256)
void prep_w(const float* __restrict__ Wq, const float* __restrict__ Wk,
            const float* __restrict__ Wv, ushort* __restrict__ Wt)
{
    const int id = blockIdx.x * 256 + threadIdx.x;   // 0..40959
    const int g  = id / 2560;
    const int r1 = id - g * 2560;
    const int s  = r1 >> 6, l = r1 & 63;
    int f, hl, ks;
    if (s < 32) { f = s >> 2; hl = (s >> 1) & 1; ks = s & 1; }
    else        { int t = s - 32; f = 8 + (t >> 1); hl = 0; ks = t & 1; }
    const float* W = (f < 4) ? Wq : (f < 8) ? Wk : Wv;
    const int col = (f & 3) * 16 + (l & 15);
    const int k   = g * 64 + ks * 32 + (l >> 4) * 8;
    float4 v0 = *(const float4*)&W[(size_t)col * EMBED + k];
    float4 v1 = *(const float4*)&W[(size_t)col * EMBED + k + 4];
    const float vv[8] = {v0.x, v0.y, v0.z, v0.w, v1.x, v1.y, v1.z, v1.w};
    ushort o[8];
#pragma unroll
    for (int i = 0; i < 8; ++i) {
        const ushort h = f2bf(vv[i]);
        o[i] = hl ? f2bf(vv[i] - bf2f(h)) : h;
    }
    *(uint4*)&Wt[((size_t)g * 40 + s) * 512 + l * 8] = pack8(o);
}

// ---------------------------------------------------------------------------
// qkv GEMM. 256 thr = 4 waves; wave w owns frags {w (Q), w+4 (K), w+8 (V)},
// all BM rows. LDS slice = 1KB; read/write addr = slicebase + lane*16B.
// ---------------------------------------------------------------------------
template<int RF, int KSP>
__global__ __launch_bounds__(256)
void qkv_mfma_t(const float* __restrict__ x, const ushort* __restrict__ Wt,
                float* __restrict__ P2)
{
    constexpr int BM = RF * 16;
    constexpr int CH = 1024 / (KSP * 64);
    __shared__ ushort SA[RF * 4 * 512];
    __shared__ ushort SB[40 * 512];

    const int tid  = threadIdx.x;
    const int w    = tid >> 6;
    const int lane = tid & 63;
    const int bid  = blockIdx.x;
    const int kz   = (KSP == 1) ? 0 : (bid & 1);
    const int mt   = (KSP == 1) ? bid : (bid >> 1);
    const int row0 = mt * BM;
    const int g0   = kz * CH;

    f32x4 acc[RF][3];
#pragma unroll
    for (int rf = 0; rf < RF; ++rf)
#pragma unroll
        for (int fi = 0; fi < 3; ++fi) acc[rf][fi] = (f32x4){0.f, 0.f, 0.f, 0.f};

    // staging identities
    const int  xrow = tid >> 3;       // 0..31
    const int  xk   = tid & 7;        // k-cell (8 bf16) within BK=64
    const bool xact = (xrow < BM);
    uint4  wreg[10];
    float4 xa, xb;

    // ---- prologue: load + commit chunk 0 ----
    {
        const int g = g0;
#pragma unroll
        for (int i = 0; i < 10; ++i) {
            const int cell = tid + 256 * i, s = cell >> 6, l = cell & 63;
            wreg[i] = *(const uint4*)&Wt[((size_t)g * 40 + s) * 512 + l * 8];
        }
        if (xact) {
            const float* xp = &x[(size_t)(row0 + xrow) * EMBED + g * 64 + xk * 8];
            xa = *(const float4*)xp; xb = *(const float4*)(xp + 4);
        }
#pragma unroll
        for (int i = 0; i < 10; ++i) {
            const int cell = tid + 256 * i, s = cell >> 6, l = cell & 63;
            *(uint4*)&SB[s * 512 + l * 8] = wreg[i];
        }
        if (xact) {
            const float vv[8] = {xa.x, xa.y, xa.z, xa.w, xb.x, xb.y, xb.z, xb.w};
            ushort hs[8], ls[8];
#pragma unroll
            for (int i = 0; i < 8; ++i) {
                hs[i] = f2bf(vv[i]); ls[i] = f2bf(vv[i] - bf2f(hs[i]));
            }
            const int rf = xrow >> 4, rowin = xrow & 15, ks = xk >> 2, oc = xk & 3;
            const int base = ((rf * 2) * 2 + ks) * 512 + oc * 128 + rowin * 8;
            *(uint4*)&SA[base]        = pack8(hs);
            *(uint4*)&SA[base + 1024] = pack8(ls);   // hl=1 -> +2 slices
        }
    }
    __syncthreads();

    for (int c = 0; c < CH; ++c) {
        // ---- issue next chunk's global loads ----
        if (c + 1 < CH) {
            const int g = g0 + c + 1;
#pragma unroll
            for (int i = 0; i < 10; ++i) {
                const int cell = tid + 256 * i, s = cell >> 6, l = cell & 63;
                wreg[i] = *(const uint4*)&Wt[((size_t)g * 40 + s) * 512 + l * 8];
            }
            if (xact) {
                const float* xp = &x[(size_t)(row0 + xrow) * EMBED + g * 64 + xk * 8];
                xa = *(const float4*)xp; xb = *(const float4*)(xp + 4);
            }
        }
        // ---- MFMA on current buffer ----
#pragma unroll
        for (int ks = 0; ks < 2; ++ks) {
            bf16x8 ah[RF], al[RF];
#pragma unroll
            for (int rf = 0; rf < RF; ++rf) {
                ah[rf] = *(const bf16x8*)&SA[((rf * 2 + 0) * 2 + ks) * 512 + lane * 8];
                al[rf] = *(const bf16x8*)&SA[((rf * 2 + 1) * 2 + ks) * 512 + lane * 8];
            }
#pragma unroll
            for (int fi = 0; fi < 2; ++fi) {              // Q, K frags: split
                const int f = w + 4 * fi;
                bf16x8 bh = *(const bf16x8*)&SB[(f * 4 + ks) * 512 + lane * 8];
                bf16x8 bl = *(const bf16x8*)&SB[(f * 4 + 2 + ks) * 512 + lane * 8];
#pragma unroll
                for (int rf = 0; rf < RF; ++rf) {
                    acc[rf][fi] = __builtin_amdgcn_mfma_f32_16x16x32_bf16(ah[rf], bh, acc[rf][fi], 0, 0, 0);
                    acc[rf][fi] = __builtin_amdgcn_mfma_f32_16x16x32_bf16(ah[rf], bl, acc[rf][fi], 0, 0, 0);
                    acc[rf][fi] = __builtin_amdgcn_mfma_f32_16x16x32_bf16(al[rf], bh, acc[rf][fi], 0, 0, 0);
                }
            }
            {                                              // V frag: hi only
                bf16x8 bv = *(const bf16x8*)&SB[(32 + w * 2 + ks) * 512 + lane * 8];
#pragma unroll
                for (int rf = 0; rf < RF; ++rf)
                    acc[rf][2] = __builtin_amdgcn_mfma_f32_16x16x32_bf16(ah[rf], bv, acc[rf][2], 0, 0, 0);
            }
        }
        __syncthreads();
        // ---- commit staged regs ----
        if (c + 1 < CH) {
#pragma unroll
            for (int i = 0; i < 10; ++i) {
                const int cell = tid + 256 * i, s = cell >> 6, l = cell & 63;
                *(uint4*)&SB[s * 512 + l * 8] = wreg[i];
            }
            if (xact) {
                const float vv[8] = {xa.x, xa.y, xa.z, xa.w, xb.x, xb.y, xb.z, xb.w};
                ushort hs[8], ls[8];
#pragma unroll
                for (int i = 0; i < 8; ++i) {
                    hs[i] = f2bf(vv[i]); ls[i] = f2bf(vv[i] - bf2f(hs[i]));
                }
                const int rf = xrow >> 4, rowin = xrow & 15, ks = xk >> 2, oc = xk & 3;
                const int base = ((rf * 2) * 2 + ks) * 512 + oc * 128 + rowin * 8;
                *(uint4*)&SA[base]        = pack8(hs);
                *(uint4*)&SA[base + 1024] = pack8(ls);
            }
        }
        __syncthreads();
    }

    // ---- epilogue: partial P (f32). D: row=(l>>4)*4+r, col=l&15 ----
    float* Pout = P2 + (size_t)kz * 3 * NROW * HEAD;
#pragma unroll
    for (int rf = 0; rf < RF; ++rf)
#pragma unroll
        for (int fi = 0; fi < 3; ++fi) {
            const int f     = w + 4 * fi;
            const int which = f >> 2;
            const int colw  = (f & 3) * 16 + (lane & 15);
#pragma unroll
            for (int r = 0; r < 4; ++r) {
                const int row = row0 + rf * 16 + (lane >> 4) * 4 + r;
                Pout[((size_t)which * NROW + row) * HEAD + colw] = acc[rf][fi][r];
            }
        }
}

// ---------------------------------------------------------------------------
// reduce_repack: bid<512: elementwise Q (x32, split) / K (split);
// bid 512..543: V transpose -> Vt bf16 [b][d][t]. H: sum K-split halves.
// ---------------------------------------------------------------------------
template<bool H>
__global__ __launch_bounds__(256)
void reduce_repack(const float* __restrict__ P2,
                   ushort* __restrict__ Qh, ushort* __restrict__ Ql,
                   ushort* __restrict__ Kh, ushort* __restrict__ Kl,
                   ushort* __restrict__ Vt)
{
    const size_t HS  = (size_t)3 * NROW * HEAD;
    const int bid = blockIdx.x, tid = threadIdx.x;
    if (bid < 512) {
        const int which = bid >> 8;
        ushort* Oh = which ? Kh : Qh;
        ushort* Ol = which ? Kl : Ql;
        const float sc = which ? 1.f : 32.f;
        const float* B0 = P2 + (size_t)which * NROW * HEAD;
#pragma unroll
        for (int j = 0; j < 2; ++j) {
            const int fidx = (bid & 255) * 512 + j * 256 + tid;
            float4 a = *(const float4*)&B0[(size_t)fidx * 4];
            if (H) {
                float4 b2 = *(const float4*)&B0[HS + (size_t)fidx * 4];
                a.x += b2.x; a.y += b2.y; a.z += b2.z; a.w += b2.w;
            }
            const float vv[4] = {sc * a.x, sc * a.y, sc * a.z, sc * a.w};
            ushort h[4], l[4];
#pragma unroll
            for (int i = 0; i < 4; ++i) {
                h[i] = f2bf(vv[i]); l[i] = f2bf(vv[i] - bf2f(h[i]));
            }
            *(ushort4*)&Oh[(size_t)fidx * 4] = make_ushort4(h[0], h[1], h[2], h[3]);
            *(ushort4*)&Ol[(size_t)fidx * 4] = make_ushort4(l[0], l[1], l[2], l[3]);
        }
    } else {
        __shared__ ushort T[64][264];
        const int s  = bid - 512;                 // 0..31
        const int b  = s >> 3;
        const int k0 = (s & 7) * 256;
        const float* V0 = P2 + (size_t)2 * NROW * HEAD;
#pragma unroll
        for (int i = 0; i < 16; ++i) {
            const int u = tid + 256 * i;          // 0..4095
            const int row = u >> 4, c4 = u & 15;
            const size_t gi = ((size_t)(b * SEQ + k0 + row)) * HEAD + c4 * 4;
            float4 v = *(const float4*)&V0[gi];
            if (H) {
                float4 v1 = *(const float4*)&V0[HS + gi];
                v.x += v1.x; v.y += v1.y; v.z += v1.z; v.w += v1.w;
            }
            T[4 * c4 + 0][row] = f2bf(v.x);
            T[4 * c4 + 1][row] = f2bf(v.y);
            T[4 * c4 + 2][row] = f2bf(v.z);
            T[4 * c4 + 3][row] = f2bf(v.w);
        }
        __syncthreads();
#pragma unroll
        for (int i = 0; i < 8; ++i) {
            const int u = tid + 256 * i;          // 0..2047
            const int d = u >> 5, c8 = u & 31;
            uint4 val = *(const uint4*)&T[d][c8 * 8];
            *(uint4*)&Vt[((size_t)(b * 64 + d)) * SEQ + k0 + c8 * 8] = val;
        }
    }
}

// ---------------------------------------------------------------------------
// attn_mfma (round-7 verified structure): 2 waves x 16q, 64-key swizzled LDS
// tiles; swapped QK^T -> lane-local softmax; P via swizzled LDS to PV A-frag.
// Q now pre-split bf16 (scale folded).
// ---------------------------------------------------------------------------
__global__ __launch_bounds__(128)
void attn_mfma(const ushort* __restrict__ Qh, const ushort* __restrict__ Ql,
               const ushort* __restrict__ Kh, const ushort* __restrict__ Kl,
               const ushort* __restrict__ Vt, char* __restrict__ PO)
{
    const int id = blockIdx.x;            // 0..639
    const int b  = id / 160;
    const int f  = id - 160 * b;
    int G, u;
    if (f < 16)      { G = 0; u = f; }
    else if (f < 48) { G = 1; u = f - 16; }
    else if (f < 96) { G = 2; u = f - 48; }
    else             { G = 3; u = f - 96; }
    const int qb  = 16 * G + u / (G + 1);
    const int kc  = u % (G + 1);
    const int q0  = qb * 32;
    const int ktd = qb >> 1;
    const int nt  = ktd + 1;
    const int t0  = kc * 8;
    const int t1  = (t0 + 8 < nt) ? t0 + 8 : nt;

    const int tid = threadIdx.x;
    const int w   = tid >> 6;
    const int lane = tid & 63;
    const int g = lane >> 4, c = lane & 15;
    const int swz = (c & 7) << 3;

    __shared__ ushort KH[64 * 64];
    __shared__ ushort KL[64 * 64];
    __shared__ ushort VT[64 * 64];
    __shared__ ushort PS[2][16 * 64];

    // ---- Q frags: pre-split bf16, scale already folded ----
    const int qrow = q0 + 16 * w + c;
    bf16x8 qh[2], ql[2];
#pragma unroll
    for (int ks = 0; ks < 2; ++ks) {
        const size_t qi = ((size_t)(b * SEQ + qrow)) * HEAD + 32 * ks + 8 * g;
        qh[ks] = *(const bf16x8*)&Qh[qi];
        ql[ks] = *(const bf16x8*)&Ql[qi];
    }

    f32x4 o[4];
#pragma unroll
    for (int db = 0; db < 4; ++db) o[db] = (f32x4){0.f, 0.f, 0.f, 0.f};
    float m = -1e30f, lsum = 0.f;

    for (int kt = t0; kt < t1; ++kt) {
        const int kb0 = kt * 64;
        __syncthreads();
#pragma unroll
        for (int i = 0; i < 4; ++i) {
            const int u2  = tid + 128 * i;
            const int row = u2 >> 3, c8 = u2 & 7;
            const int dst = row * 64 + ((c8 ^ (row & 7)) * 8);
            const size_t ksrc = ((size_t)(b * SEQ + kb0 + row)) * HEAD + c8 * 8;
            *(uint4*)&KH[dst] = *(const uint4*)&Kh[ksrc];
            *(uint4*)&KL[dst] = *(const uint4*)&Kl[ksrc];
            const size_t vsrc = ((size_t)(b * 64 + row)) * SEQ + kb0 + c8 * 8;
            *(uint4*)&VT[dst] = *(const uint4*)&Vt[vsrc];
        }
        __syncthreads();

        f32x4 s[4];
#pragma unroll
        for (int kb = 0; kb < 4; ++kb) s[kb] = (f32x4){0.f, 0.f, 0.f, 0.f};
#pragma unroll
        for (int ks = 0; ks < 2; ++ks) {
            const int co = (32 * ks + 8 * g) ^ swz;
#pragma unroll
            for (int kb = 0; kb < 4; ++kb) {
                const int row = 16 * kb + c;
                bf16x8 ah = *(const bf16x8*)&KH[row * 64 + co];
                bf16x8 al = *(const bf16x8*)&KL[row * 64 + co];
                s[kb] = __builtin_amdgcn_mfma_f32_16x16x32_bf16(ah, qh[ks], s[kb], 0, 0, 0);
                s[kb] = __builtin_amdgcn_mfma_f32_16x16x32_bf16(ah, ql[ks], s[kb], 0, 0, 0);
                s[kb] = __builtin_amdgcn_mfma_f32_16x16x32_bf16(al, qh[ks], s[kb], 0, 0, 0);
            }
        }

        if (kt == ktd) {
#pragma unroll
            for (int kb = 0; kb < 4; ++kb)
#pragma unroll
                for (int r = 0; r < 4; ++r)
                    if (kb0 + 16 * kb + 4 * g + r > qrow) s[kb][r] = -1e30f;
        }

        float tmax = -1e30f;
#pragma unroll
        for (int kb = 0; kb < 4; ++kb) {
            float a = fmaxf(fmaxf(s[kb][0], s[kb][1]), fmaxf(s[kb][2], s[kb][3]));
            tmax = fmaxf(tmax, a);
        }
        tmax = fmaxf(tmax, __shfl_xor(tmax, 16));
        tmax = fmaxf(tmax, __shfl_xor(tmax, 32));
        const float mnew = fmaxf(m, tmax);
        const float fac  = __expf(m - mnew);
        float p[4][4];
        float psum = 0.f;
#pragma unroll
        for (int kb = 0; kb < 4; ++kb)
#pragma unroll
            for (int r = 0; r < 4; ++r) {
                p[kb][r] = __expf(s[kb][r] - mnew);
                psum += p[kb][r];
            }
        psum += __shfl_xor(psum, 16);
        psum += __shfl_xor(psum, 32);
        lsum = lsum * fac + psum;
        m = mnew;

        float fb[4];
#pragma unroll
        for (int r = 0; r < 4; ++r) fb[r] = __shfl(fac, 4 * g + r);
#pragma unroll
        for (int db = 0; db < 4; ++db) {
            o[db][0] *= fb[0]; o[db][1] *= fb[1];
            o[db][2] *= fb[2]; o[db][3] *= fb[3];
        }

#pragma unroll
        for (int kb = 0; kb < 4; ++kb) {
            const int idx = c * 64 + (((16 * kb + 4 * g)) ^ swz);
            *(ushort4*)&PS[w][idx] = make_ushort4(
                f2bf(p[kb][0]), f2bf(p[kb][1]), f2bf(p[kb][2]), f2bf(p[kb][3]));
        }

#pragma unroll
        for (int k2 = 0; k2 < 2; ++k2) {
            const int co = (32 * k2 + 8 * g) ^ swz;
            bf16x8 pa = *(const bf16x8*)&PS[w][c * 64 + co];
#pragma unroll
            for (int db = 0; db < 4; ++db) {
                const int row = 16 * db + c;
                bf16x8 vb = *(const bf16x8*)&VT[row * 64 + co];
                o[db] = __builtin_amdgcn_mfma_f32_16x16x32_bf16(pa, vb, o[db], 0, 0, 0);
            }
        }
    }

    char* item = PO + (size_t)id * 4352;
    ushort* po = (ushort*)item;
    float*  ml = (float*)(item + 4096);
#pragma unroll
    for (int db = 0; db < 4; ++db)
#pragma unroll
        for (int r = 0; r < 4; ++r) {
            const int qq = 16 * w + 4 * g + r;
            po[qq * 64 + 16 * db + c] = f2bf(o[db][r]);
        }
    if (g == 0) {
        ml[16 * w + c]      = m;
        ml[32 + 16 * w + c] = lsum;
    }
}

// ---------------------------------------------------------------------------
__global__ __launch_bounds__(256)
void attn_combine(const char* __restrict__ PO, float* __restrict__ out)
{
    const int qbg = blockIdx.x;            // 0..255
    const int b   = qbg >> 6, qb = qbg & 63;
    const int G   = qb >> 4, np = G + 1;
    const int base = b * 160 + (G + 1) * (qb - 8 * G);
    const int tid = threadIdx.x;
    const int row = tid >> 3, c8 = tid & 7;

    float M = -1e30f;
    for (int p = 0; p < np; ++p) {
        const float* ml = (const float*)(PO + (size_t)(base + p) * 4352 + 4096);
        M = fmaxf(M, ml[row]);
    }
    float L = 0.f;
    float acc[8];
#pragma unroll
    for (int j = 0; j < 8; ++j) acc[j] = 0.f;
    for (int p = 0; p < np; ++p) {
        const char* item = PO + (size_t)(base + p) * 4352;
        const float* ml  = (const float*)(item + 4096);
        const float wgt  = __expf(ml[row] - M);
        L += wgt * ml[32 + row];
        const ushort* po = (const ushort*)item;
        ushort4 a0 = *(const ushort4*)&po[row * 64 + c8 * 8];
        ushort4 a1 = *(const ushort4*)&po[row * 64 + c8 * 8 + 4];
        acc[0] += wgt * bf2f(a0.x); acc[1] += wgt * bf2f(a0.y);
        acc[2] += wgt * bf2f(a0.z); acc[3] += wgt * bf2f(a0.w);
        acc[4] += wgt * bf2f(a1.x); acc[5] += wgt * bf2f(a1.y);
        acc[6] += wgt * bf2f(a1.z); acc[7] += wgt * bf2f(a1.w);
    }
    const float inv = 1.f / L;
    float* dst = &out[((size_t)(b * SEQ + qb * 32 + row)) * HEAD + c8 * 8];
    *(float4*)dst       = make_float4(acc[0] * inv, acc[1] * inv, acc[2] * inv, acc[3] * inv);
    *(float4*)(dst + 4) = make_float4(acc[4] * inv, acc[5] * inv, acc[6] * inv, acc[7] * inv);
}

// ---------------------------------------------------------------------------

extern "C" void kernel_launch(void* const* d_in, const int* in_sizes, int n_in,
                              void* d_out, int out_size, void* d_ws, size_t ws_size,
                              hipStream_t stream)
{
    // setup_inputs order: x, Wk, Wq, Wv
    const float* x  = (const float*)d_in[0];
    const float* Wk = (const float*)d_in[1];
    const float* Wq = (const float*)d_in[2];
    const float* Wv = (const float*)d_in[3];

    char* ws = (char*)d_ws;
    const bool big = (ws_size >= (size_t)18481152);

    // buffer layout (bytes)
    const size_t P2_SZ = big ? 12582912 : 6291456;     // f32 partials (x2 or x1)
    const size_t WT_OFF = P2_SZ;
    const size_t QH_OFF = WT_OFF + 655360;
    const size_t QL_OFF = QH_OFF + 1048576;
    const size_t KH_OFF = QL_OFF + 1048576;
    const size_t KL_OFF = KH_OFF + 1048576;
    const size_t VT_OFF = KL_OFF + 1048576;

    float*  P2  = (float*)ws;
    ushort* Wt  = (ushort*)(ws + WT_OFF);
    ushort* Qh  = (ushort*)(ws + QH_OFF);
    ushort* Ql  = (ushort*)(ws + QL_OFF);
    ushort* Kh  = (ushort*)(ws + KH_OFF);
    ushort* Kl  = (ushort*)(ws + KL_OFF);
    ushort* Vt  = (ushort*)(ws + VT_OFF);
    char*   PO  = ws;                                  // aliases P2 (dead)

    prep_w<<<dim3(160), 256, 0, stream>>>(Wq, Wk, Wv, Wt);
    if (big) {
        qkv_mfma_t<2, 2><<<dim3(512), 256, 0, stream>>>(x, Wt, P2);
        reduce_repack<true><<<dim3(544), 256, 0, stream>>>(P2, Qh, Ql, Kh, Kl, Vt);
    } else {
        qkv_mfma_t<1, 1><<<dim3(512), 256, 0, stream>>>(x, Wt, P2);
        reduce_repack<false><<<dim3(544), 256, 0, stream>>>(P2, Qh, Ql, Kh, Kl, Vt);
    }
    attn_mfma   <<<dim3(640), 128, 0, stream>>>(Qh, Ql, Kh, Kl, Vt, PO);
    attn_combine<<<dim3(256), 256, 0, stream>>>(PO, (float*)d_out);
}

// Round 10
// 92.432 us; speedup vs baseline: 4.3830x; 1.0049x over previous
//
#include <hip/hip_runtime.h>
#include <math.h>

#define EMBED 1024
#define SEQ   2048
#define HEAD  64
#define NROW  8192   /* BATCH*SEQ */

// ---------------------------------------------------------------------------
// Round 10: fix HBM write amplification (WRITE_SIZE 160MB for 12.58MB useful).
//  - qkv epilogue: acc -> LDS transpose (SB reused, pad-68 rows) -> fully
//    coalesced 1KB-per-wave f32 stores. Everything else identical to round 9.
//  - attn_mfma epilogue: po staged in KH-as-scratch, copied out as contiguous
//    uint4 (was 2B/lane scattered).
// Theory: round-9 qkv was bound by sub-line scattered MFMA-D-layout stores
// (193MB HBM @2.4TB/s = 71us). Coalescing removes ~147MB of write traffic.
// ---------------------------------------------------------------------------

typedef float f32x4  __attribute__((ext_vector_type(4)));
typedef short bf16x8 __attribute__((ext_vector_type(8)));

__device__ __forceinline__ ushort f2bf(float v) {
    union { float f; unsigned u; } t; t.f = v;
    unsigned r = t.u + 0x7FFFu + ((t.u >> 16) & 1u);   // RNE
    return (ushort)(r >> 16);
}
__device__ __forceinline__ float bf2f(ushort h) {
    union { float f; unsigned u; } t; t.u = ((unsigned)h) << 16;
    return t.f;
}
__device__ __forceinline__ uint4 pack8(const ushort* o) {
    uint4 u;
    u.x = (unsigned)o[0] | ((unsigned)o[1] << 16);
    u.y = (unsigned)o[2] | ((unsigned)o[3] << 16);
    u.z = (unsigned)o[4] | ((unsigned)o[5] << 16);
    u.w = (unsigned)o[6] | ((unsigned)o[7] << 16);
    return u;
}

// ---------------------------------------------------------------------------
__global__ __launch_bounds__(256)
void prep_w(const float* __restrict__ Wq, const float* __restrict__ Wk,
            const float* __restrict__ Wv, ushort* __restrict__ Wt)
{
    const int id = blockIdx.x * 256 + threadIdx.x;   // 0..40959
    const int g  = id / 2560;
    const int r1 = id - g * 2560;
    const int s  = r1 >> 6, l = r1 & 63;
    int f, hl, ks;
    if (s < 32) { f = s >> 2; hl = (s >> 1) & 1; ks = s & 1; }
    else        { int t = s - 32; f = 8 + (t >> 1); hl = 0; ks = t & 1; }
    const float* W = (f < 4) ? Wq : (f < 8) ? Wk : Wv;
    const int col = (f & 3) * 16 + (l & 15);
    const int k   = g * 64 + ks * 32 + (l >> 4) * 8;
    float4 v0 = *(const float4*)&W[(size_t)col * EMBED + k];
    float4 v1 = *(const float4*)&W[(size_t)col * EMBED + k + 4];
    const float vv[8] = {v0.x, v0.y, v0.z, v0.w, v1.x, v1.y, v1.z, v1.w};
    ushort o[8];
#pragma unroll
    for (int i = 0; i < 8; ++i) {
        const ushort h = f2bf(vv[i]);
        o[i] = hl ? f2bf(vv[i] - bf2f(h)) : h;
    }
    *(uint4*)&Wt[((size_t)g * 40 + s) * 512 + l * 8] = pack8(o);
}

// ---------------------------------------------------------------------------
// qkv GEMM. 256 thr = 4 waves; wave w owns frags {w (Q), w+4 (K), w+8 (V)}.
// LDS slice = 1KB; read/write addr = slicebase + lane*16B (conflict-free).
// Epilogue: LDS transpose -> coalesced 1KB/wave stores.
// ---------------------------------------------------------------------------
template<int RF, int KSP>
__global__ __launch_bounds__(256)
void qkv_mfma_t(const float* __restrict__ x, const ushort* __restrict__ Wt,
                float* __restrict__ P2)
{
    constexpr int BM = RF * 16;
    constexpr int CH = 1024 / (KSP * 64);
    __shared__ ushort SA[RF * 4 * 512];
    __shared__ ushort SB[40 * 512];     // also epilogue scratch [3][BM][68] f32

    const int tid  = threadIdx.x;
    const int w    = tid >> 6;
    const int lane = tid & 63;
    const int bid  = blockIdx.x;
    const int kz   = (KSP == 1) ? 0 : (bid & 1);
    const int mt   = (KSP == 1) ? bid : (bid >> 1);
    const int row0 = mt * BM;
    const int g0   = kz * CH;

    f32x4 acc[RF][3];
#pragma unroll
    for (int rf = 0; rf < RF; ++rf)
#pragma unroll
        for (int fi = 0; fi < 3; ++fi) acc[rf][fi] = (f32x4){0.f, 0.f, 0.f, 0.f};

    // staging identities
    const int  xrow = tid >> 3;       // 0..31
    const int  xk   = tid & 7;        // k-cell (8 bf16) within BK=64
    const bool xact = (xrow < BM);
    uint4  wreg[10];
    float4 xa, xb;

    // ---- prologue: load + commit chunk 0 ----
    {
        const int g = g0;
#pragma unroll
        for (int i = 0; i < 10; ++i) {
            const int cell = tid + 256 * i, s = cell >> 6, l = cell & 63;
            wreg[i] = *(const uint4*)&Wt[((size_t)g * 40 + s) * 512 + l * 8];
        }
        if (xact) {
            const float* xp = &x[(size_t)(row0 + xrow) * EMBED + g * 64 + xk * 8];
            xa = *(const float4*)xp; xb = *(const float4*)(xp + 4);
        }
#pragma unroll
        for (int i = 0; i < 10; ++i) {
            const int cell = tid + 256 * i, s = cell >> 6, l = cell & 63;
            *(uint4*)&SB[s * 512 + l * 8] = wreg[i];
        }
        if (xact) {
            const float vv[8] = {xa.x, xa.y, xa.z, xa.w, xb.x, xb.y, xb.z, xb.w};
            ushort hs[8], ls[8];
#pragma unroll
            for (int i = 0; i < 8; ++i) {
                hs[i] = f2bf(vv[i]); ls[i] = f2bf(vv[i] - bf2f(hs[i]));
            }
            const int rf = xrow >> 4, rowin = xrow & 15, ks = xk >> 2, oc = xk & 3;
            const int base = ((rf * 2) * 2 + ks) * 512 + oc * 128 + rowin * 8;
            *(uint4*)&SA[base]        = pack8(hs);
            *(uint4*)&SA[base + 1024] = pack8(ls);   // hl=1 -> +2 slices
        }
    }
    __syncthreads();

    for (int c = 0; c < CH; ++c) {
        // ---- issue next chunk's global loads ----
        if (c + 1 < CH) {
            const int g = g0 + c + 1;
#pragma unroll
            for (int i = 0; i < 10; ++i) {
                const int cell = tid + 256 * i, s = cell >> 6, l = cell & 63;
                wreg[i] = *(const uint4*)&Wt[((size_t)g * 40 + s) * 512 + l * 8];
            }
            if (xact) {
                const float* xp = &x[(size_t)(row0 + xrow) * EMBED + g * 64 + xk * 8];
                xa = *(const float4*)xp; xb = *(const float4*)(xp + 4);
            }
        }
        // ---- MFMA on current buffer ----
#pragma unroll
        for (int ks = 0; ks < 2; ++ks) {
            bf16x8 ah[RF], al[RF];
#pragma unroll
            for (int rf = 0; rf < RF; ++rf) {
                ah[rf] = *(const bf16x8*)&SA[((rf * 2 + 0) * 2 + ks) * 512 + lane * 8];
                al[rf] = *(const bf16x8*)&SA[((rf * 2 + 1) * 2 + ks) * 512 + lane * 8];
            }
#pragma unroll
            for (int fi = 0; fi < 2; ++fi) {              // Q, K frags: split
                const int f = w + 4 * fi;
                bf16x8 bh = *(const bf16x8*)&SB[(f * 4 + ks) * 512 + lane * 8];
                bf16x8 bl = *(const bf16x8*)&SB[(f * 4 + 2 + ks) * 512 + lane * 8];
#pragma unroll
                for (int rf = 0; rf < RF; ++rf) {
                    acc[rf][fi] = __builtin_amdgcn_mfma_f32_16x16x32_bf16(ah[rf], bh, acc[rf][fi], 0, 0, 0);
                    acc[rf][fi] = __builtin_amdgcn_mfma_f32_16x16x32_bf16(ah[rf], bl, acc[rf][fi], 0, 0, 0);
                    acc[rf][fi] = __builtin_amdgcn_mfma_f32_16x16x32_bf16(al[rf], bh, acc[rf][fi], 0, 0, 0);
                }
            }
            {                                              // V frag: hi only
                bf16x8 bv = *(const bf16x8*)&SB[(32 + w * 2 + ks) * 512 + lane * 8];
#pragma unroll
                for (int rf = 0; rf < RF; ++rf)
                    acc[rf][2] = __builtin_amdgcn_mfma_f32_16x16x32_bf16(ah[rf], bv, acc[rf][2], 0, 0, 0);
            }
        }
        __syncthreads();
        // ---- commit staged regs ----
        if (c + 1 < CH) {
#pragma unroll
            for (int i = 0; i < 10; ++i) {
                const int cell = tid + 256 * i, s = cell >> 6, l = cell & 63;
                *(uint4*)&SB[s * 512 + l * 8] = wreg[i];
            }
            if (xact) {
                const float vv[8] = {xa.x, xa.y, xa.z, xa.w, xb.x, xb.y, xb.z, xb.w};
                ushort hs[8], ls[8];
#pragma unroll
                for (int i = 0; i < 8; ++i) {
                    hs[i] = f2bf(vv[i]); ls[i] = f2bf(vv[i] - bf2f(hs[i]));
                }
                const int rf = xrow >> 4, rowin = xrow & 15, ks = xk >> 2, oc = xk & 3;
                const int base = ((rf * 2) * 2 + ks) * 512 + oc * 128 + rowin * 8;
                *(uint4*)&SA[base]        = pack8(hs);
                *(uint4*)&SA[base + 1024] = pack8(ls);
            }
        }
        __syncthreads();
    }

    // ---- epilogue: acc -> LDS transpose -> coalesced stores ----
    // T layout: [which 3][row BM][68] f32 (pad 68: 2-way-max write conflicts,
    // row stride 272B = 17*16B keeps float4 alignment). Fits SB (<=26.1KB).
    __syncthreads();
    float* T = (float*)SB;
#pragma unroll
    for (int rf = 0; rf < RF; ++rf)
#pragma unroll
        for (int fi = 0; fi < 3; ++fi) {
            const int f     = w + 4 * fi;
            const int which = f >> 2;
            const int colw  = w * 16 + (lane & 15);   // (f&3)==w for all fi
#pragma unroll
            for (int r = 0; r < 4; ++r) {
                const int row = rf * 16 + (lane >> 4) * 4 + r;
                T[(which * BM + row) * 68 + colw] = acc[rf][fi][r];
            }
        }
    __syncthreads();
    constexpr int NF4 = 3 * BM * 16;                  // float4 count
    float* Pout = P2 + (size_t)kz * 3 * NROW * HEAD;
#pragma unroll
    for (int u0 = 0; u0 < NF4; u0 += 256) {
        const int u     = u0 + tid;
        const int which = u / (BM * 16);
        const int rem   = u - which * (BM * 16);
        const int row   = rem >> 4, c4 = rem & 15;
        float4 v = *(const float4*)&T[(which * BM + row) * 68 + c4 * 4];
        *(float4*)&Pout[((size_t)which * NROW + row0 + row) * HEAD + c4 * 4] = v;
    }
}

// ---------------------------------------------------------------------------
// reduce_repack: bid<512: elementwise Q (x32, split) / K (split);
// bid 512..543: V transpose -> Vt bf16 [b][d][t]. H: sum K-split halves.
// ---------------------------------------------------------------------------
template<bool H>
__global__ __launch_bounds__(256)
void reduce_repack(const float* __restrict__ P2,
                   ushort* __restrict__ Qh, ushort* __restrict__ Ql,
                   ushort* __restrict__ Kh, ushort* __restrict__ Kl,
                   ushort* __restrict__ Vt)
{
    const size_t HS  = (size_t)3 * NROW * HEAD;
    const int bid = blockIdx.x, tid = threadIdx.x;
    if (bid < 512) {
        const int which = bid >> 8;
        ushort* Oh = which ? Kh : Qh;
        ushort* Ol = which ? Kl : Ql;
        const float sc = which ? 1.f : 32.f;
        const float* B0 = P2 + (size_t)which * NROW * HEAD;
#pragma unroll
        for (int j = 0; j < 2; ++j) {
            const int fidx = (bid & 255) * 512 + j * 256 + tid;
            float4 a = *(const float4*)&B0[(size_t)fidx * 4];
            if (H) {
                float4 b2 = *(const float4*)&B0[HS + (size_t)fidx * 4];
                a.x += b2.x; a.y += b2.y; a.z += b2.z; a.w += b2.w;
            }
            const float vv[4] = {sc * a.x, sc * a.y, sc * a.z, sc * a.w};
            ushort h[4], l[4];
#pragma unroll
            for (int i = 0; i < 4; ++i) {
                h[i] = f2bf(vv[i]); l[i] = f2bf(vv[i] - bf2f(h[i]));
            }
            *(ushort4*)&Oh[(size_t)fidx * 4] = make_ushort4(h[0], h[1], h[2], h[3]);
            *(ushort4*)&Ol[(size_t)fidx * 4] = make_ushort4(l[0], l[1], l[2], l[3]);
        }
    } else {
        __shared__ ushort T[64][264];
        const int s  = bid - 512;                 // 0..31
        const int b  = s >> 3;
        const int k0 = (s & 7) * 256;
        const float* V0 = P2 + (size_t)2 * NROW * HEAD;
#pragma unroll
        for (int i = 0; i < 16; ++i) {
            const int u = tid + 256 * i;          // 0..4095
            const int row = u >> 4, c4 = u & 15;
            const size_t gi = ((size_t)(b * SEQ + k0 + row)) * HEAD + c4 * 4;
            float4 v = *(const float4*)&V0[gi];
            if (H) {
                float4 v1 = *(const float4*)&V0[HS + gi];
                v.x += v1.x; v.y += v1.y; v.z += v1.z; v.w += v1.w;
            }
            T[4 * c4 + 0][row] = f2bf(v.x);
            T[4 * c4 + 1][row] = f2bf(v.y);
            T[4 * c4 + 2][row] = f2bf(v.z);
            T[4 * c4 + 3][row] = f2bf(v.w);
        }
        __syncthreads();
#pragma unroll
        for (int i = 0; i < 8; ++i) {
            const int u = tid + 256 * i;          // 0..2047
            const int d = u >> 5, c8 = u & 31;
            uint4 val = *(const uint4*)&T[d][c8 * 8];
            *(uint4*)&Vt[((size_t)(b * 64 + d)) * SEQ + k0 + c8 * 8] = val;
        }
    }
}

// ---------------------------------------------------------------------------
// attn_mfma (verified structure): 2 waves x 16q, 64-key swizzled LDS tiles;
// swapped QK^T -> lane-local softmax; P via swizzled LDS to PV A-frag.
// Epilogue now coalesced via KH-as-scratch.
// ---------------------------------------------------------------------------
__global__ __launch_bounds__(128)
void attn_mfma(const ushort* __restrict__ Qh, const ushort* __restrict__ Ql,
               const ushort* __restrict__ Kh, const ushort* __restrict__ Kl,
               const ushort* __restrict__ Vt, char* __restrict__ PO)
{
    const int id = blockIdx.x;            // 0..639
    const int b  = id / 160;
    const int f  = id - 160 * b;
    int G, u;
    if (f < 16)      { G = 0; u = f; }
    else if (f < 48) { G = 1; u = f - 16; }
    else if (f < 96) { G = 2; u = f - 48; }
    else             { G = 3; u = f - 96; }
    const int qb  = 16 * G + u / (G + 1);
    const int kc  = u % (G + 1);
    const int q0  = qb * 32;
    const int ktd = qb >> 1;
    const int nt  = ktd + 1;
    const int t0  = kc * 8;
    const int t1  = (t0 + 8 < nt) ? t0 + 8 : nt;

    const int tid = threadIdx.x;
    const int w   = tid >> 6;
    const int lane = tid & 63;
    const int g = lane >> 4, c = lane & 15;
    const int swz = (c & 7) << 3;

    __shared__ ushort KH[64 * 64];
    __shared__ ushort KL[64 * 64];
    __shared__ ushort VT[64 * 64];
    __shared__ ushort PS[2][16 * 64];

    // ---- Q frags: pre-split bf16, scale already folded ----
    const int qrow = q0 + 16 * w + c;
    bf16x8 qh[2], ql[2];
#pragma unroll
    for (int ks = 0; ks < 2; ++ks) {
        const size_t qi = ((size_t)(b * SEQ + qrow)) * HEAD + 32 * ks + 8 * g;
        qh[ks] = *(const bf16x8*)&Qh[qi];
        ql[ks] = *(const bf16x8*)&Ql[qi];
    }

    f32x4 o[4];
#pragma unroll
    for (int db = 0; db < 4; ++db) o[db] = (f32x4){0.f, 0.f, 0.f, 0.f};
    float m = -1e30f, lsum = 0.f;

    for (int kt = t0; kt < t1; ++kt) {
        const int kb0 = kt * 64;
        __syncthreads();
#pragma unroll
        for (int i = 0; i < 4; ++i) {
            const int u2  = tid + 128 * i;
            const int row = u2 >> 3, c8 = u2 & 7;
            const int dst = row * 64 + ((c8 ^ (row & 7)) * 8);
            const size_t ksrc = ((size_t)(b * SEQ + kb0 + row)) * HEAD + c8 * 8;
            *(uint4*)&KH[dst] = *(const uint4*)&Kh[ksrc];
            *(uint4*)&KL[dst] = *(const uint4*)&Kl[ksrc];
            const size_t vsrc = ((size_t)(b * 64 + row)) * SEQ + kb0 + c8 * 8;
            *(uint4*)&VT[dst] = *(const uint4*)&Vt[vsrc];
        }
        __syncthreads();

        f32x4 s[4];
#pragma unroll
        for (int kb = 0; kb < 4; ++kb) s[kb] = (f32x4){0.f, 0.f, 0.f, 0.f};
#pragma unroll
        for (int ks = 0; ks < 2; ++ks) {
            const int co = (32 * ks + 8 * g) ^ swz;
#pragma unroll
            for (int kb = 0; kb < 4; ++kb) {
                const int row = 16 * kb + c;
                bf16x8 ah = *(const bf16x8*)&KH[row * 64 + co];
                bf16x8 al = *(const bf16x8*)&KL[row * 64 + co];
                s[kb] = __builtin_amdgcn_mfma_f32_16x16x32_bf16(ah, qh[ks], s[kb], 0, 0, 0);
                s[kb] = __builtin_amdgcn_mfma_f32_16x16x32_bf16(ah, ql[ks], s[kb], 0, 0, 0);
                s[kb] = __builtin_amdgcn_mfma_f32_16x16x32_bf16(al, qh[ks], s[kb], 0, 0, 0);
            }
        }

        if (kt == ktd) {
#pragma unroll
            for (int kb = 0; kb < 4; ++kb)
#pragma unroll
                for (int r = 0; r < 4; ++r)
                    if (kb0 + 16 * kb + 4 * g + r > qrow) s[kb][r] = -1e30f;
        }

        float tmax = -1e30f;
#pragma unroll
        for (int kb = 0; kb < 4; ++kb) {
            float a = fmaxf(fmaxf(s[kb][0], s[kb][1]), fmaxf(s[kb][2], s[kb][3]));
            tmax = fmaxf(tmax, a);
        }
        tmax = fmaxf(tmax, __shfl_xor(tmax, 16));
        tmax = fmaxf(tmax, __shfl_xor(tmax, 32));
        const float mnew = fmaxf(m, tmax);
        const float fac  = __expf(m - mnew);
        float p[4][4];
        float psum = 0.f;
#pragma unroll
        for (int kb = 0; kb < 4; ++kb)
#pragma unroll
            for (int r = 0; r < 4; ++r) {
                p[kb][r] = __expf(s[kb][r] - mnew);
                psum += p[kb][r];
            }
        psum += __shfl_xor(psum, 16);
        psum += __shfl_xor(psum, 32);
        lsum = lsum * fac + psum;
        m = mnew;

        float fb[4];
#pragma unroll
        for (int r = 0; r < 4; ++r) fb[r] = __shfl(fac, 4 * g + r);
#pragma unroll
        for (int db = 0; db < 4; ++db) {
            o[db][0] *= fb[0]; o[db][1] *= fb[1];
            o[db][2] *= fb[2]; o[db][3] *= fb[3];
        }

#pragma unroll
        for (int kb = 0; kb < 4; ++kb) {
            const int idx = c * 64 + (((16 * kb + 4 * g)) ^ swz);
            *(ushort4*)&PS[w][idx] = make_ushort4(
                f2bf(p[kb][0]), f2bf(p[kb][1]), f2bf(p[kb][2]), f2bf(p[kb][3]));
        }

#pragma unroll
        for (int k2 = 0; k2 < 2; ++k2) {
            const int co = (32 * k2 + 8 * g) ^ swz;
            bf16x8 pa = *(const bf16x8*)&PS[w][c * 64 + co];
#pragma unroll
            for (int db = 0; db < 4; ++db) {
                const int row = 16 * db + c;
                bf16x8 vb = *(const bf16x8*)&VT[row * 64 + co];
                o[db] = __builtin_amdgcn_mfma_f32_16x16x32_bf16(pa, vb, o[db], 0, 0, 0);
            }
        }
    }

    // ---- epilogue: po -> KH-as-scratch -> coalesced uint4 copy ----
    char* item = PO + (size_t)id * 4352;
    ushort* po = (ushort*)item;
    float*  ml = (float*)(item + 4096);
    __syncthreads();                      // all waves done with KH
    ushort* OT = KH;                      // scratch [32][64] ushort = 4KB
#pragma unroll
    for (int db = 0; db < 4; ++db)
#pragma unroll
        for (int r = 0; r < 4; ++r) {
            const int qq = 16 * w + 4 * g + r;
            OT[qq * 64 + 16 * db + c] = f2bf(o[db][r]);
        }
    if (g == 0) {
        ml[16 * w + c]      = m;
        ml[32 + 16 * w + c] = lsum;
    }
    __syncthreads();
#pragma unroll
    for (int i = 0; i < 2; ++i) {
        const int u2 = tid + 128 * i;     // 0..255 uint4 cells
        *(uint4*)&po[u2 * 8] = *(const uint4*)&OT[u2 * 8];
    }
}

// ---------------------------------------------------------------------------
__global__ __launch_bounds__(256)
void attn_combine(const char* __restrict__ PO, float* __restrict__ out)
{
    const int qbg = blockIdx.x;            // 0..255
    const int b   = qbg >> 6, qb = qbg & 63;
    const int G   = qb >> 4, np = G + 1;
    const int base = b * 160 + (G + 1) * (qb - 8 * G);
    const int tid = threadIdx.x;
    const int row = tid >> 3, c8 = tid & 7;

    float M = -1e30f;
    for (int p = 0; p < np; ++p) {
        const float* ml = (const float*)(PO + (size_t)(base + p) * 4352 + 4096);
        M = fmaxf(M, ml[row]);
    }
    float L = 0.f;
    float acc[8];
#pragma unroll
    for (int j = 0; j < 8; ++j) acc[j] = 0.f;
    for (int p = 0; p < np; ++p) {
        const char* item = PO + (size_t)(base + p) * 4352;
        const float* ml  = (const float*)(item + 4096);
        const float wgt  = __expf(ml[row] - M);
        L += wgt * ml[32 + row];
        const ushort* po = (const ushort*)item;
        ushort4 a0 = *(const ushort4*)&po[row * 64 + c8 * 8];
        ushort4 a1 = *(const ushort4*)&po[row * 64 + c8 * 8 + 4];
        acc[0] += wgt * bf2f(a0.x); acc[1] += wgt * bf2f(a0.y);
        acc[2] += wgt * bf2f(a0.z); acc[3] += wgt * bf2f(a0.w);
        acc[4] += wgt * bf2f(a1.x); acc[5] += wgt * bf2f(a1.y);
        acc[6] += wgt * bf2f(a1.z); acc[7] += wgt * bf2f(a1.w);
    }
    const float inv = 1.f / L;
    float* dst = &out[((size_t)(b * SEQ + qb * 32 + row)) * HEAD + c8 * 8];
    *(float4*)dst       = make_float4(acc[0] * inv, acc[1] * inv, acc[2] * inv, acc[3] * inv);
    *(float4*)(dst + 4) = make_float4(acc[4] * inv, acc[5] * inv, acc[6] * inv, acc[7] * inv);
}

// ---------------------------------------------------------------------------

extern "C" void kernel_launch(void* const* d_in, const int* in_sizes, int n_in,
                              void* d_out, int out_size, void* d_ws, size_t ws_size,
                              hipStream_t stream)
{
    // setup_inputs order: x, Wk, Wq, Wv
    const float* x  = (const float*)d_in[0];
    const float* Wk = (const float*)d_in[1];
    const float* Wq = (const float*)d_in[2];
    const float* Wv = (const float*)d_in[3];

    char* ws = (char*)d_ws;
    const bool big = (ws_size >= (size_t)18481152);

    // buffer layout (bytes)
    const size_t P2_SZ = big ? 12582912 : 6291456;     // f32 partials (x2 or x1)
    const size_t WT_OFF = P2_SZ;
    const size_t QH_OFF = WT_OFF + 655360;
    const size_t QL_OFF = QH_OFF + 1048576;
    const size_t KH_OFF = QL_OFF + 1048576;
    const size_t KL_OFF = KH_OFF + 1048576;
    const size_t VT_OFF = KL_OFF + 1048576;

    float*  P2  = (float*)ws;
    ushort* Wt  = (ushort*)(ws + WT_OFF);
    ushort* Qh  = (ushort*)(ws + QH_OFF);
    ushort* Ql  = (ushort*)(ws + QL_OFF);
    ushort* Kh  = (ushort*)(ws + KH_OFF);
    ushort* Kl  = (ushort*)(ws + KL_OFF);
    ushort* Vt  = (ushort*)(ws + VT_OFF);
    char*   PO  = ws;                                  // aliases P2 (dead)

    prep_w<<<dim3(160), 256, 0, stream>>>(Wq, Wk, Wv, Wt);
    if (big) {
        qkv_mfma_t<2, 2><<<dim3(512), 256, 0, stream>>>(x, Wt, P2);
        reduce_repack<true><<<dim3(544), 256, 0, stream>>>(P2, Qh, Ql, Kh, Kl, Vt);
    } else {
        qkv_mfma_t<1, 1><<<dim3(512), 256, 0, stream>>>(x, Wt, P2);
        reduce_repack<false><<<dim3(544), 256, 0, stream>>>(P2, Qh, Ql, Kh, Kl, Vt);
    }
    attn_mfma   <<<dim3(640), 128, 0, stream>>>(Qh, Ql, Kh, Kl, Vt, PO);
    attn_combine<<<dim3(256), 256, 0, stream>>>(PO, (float*)d_out);
}

// Round 11
// 60.220 us; speedup vs baseline: 6.7275x; 1.5349x over previous
//
#include <hip/hip_runtime.h>
#include <math.h>

#define EMBED 1024
#define SEQ   2048
#define HEAD  64
#define NROW  8192   /* BATCH*SEQ */

// ---------------------------------------------------------------------------
// Round 11: eliminate the f32 P2 round-trip (every 9-40x WRITE_SIZE anomaly
// across rounds is attached to it; round-10 A/B proved store PATTERN is not
// the cause).
//  K0 prep_w:    (unchanged) W f32 -> Wt MFMA-slice tiles (Q/K hi+lo, V hi).
//  K1 qkv_fused: BM=16, full K per block, grid 512 (~4 blocks/CU).
//                W frags: global->REGISTER loads (1KB contiguous per wave,
//                L2-resident) -- no W LDS staging at all. LDS = 2x4KB x tile
//                (dbuf, 1 barrier/chunk) + 13KB epilogue scratch.
//                Epilogue writes FINAL attn inputs: Qh/Ql (x32, split),
//                Kh/Kl, Vr bf16 row-major (dense 128B lines).
//  K2 v_transpose: Vr -> Vt bf16 [b][d][t] (2MB, 32 blocks).
//  K3 attn_mfma:  (unchanged, verified).
//  K4 attn_combine: (unchanged).
// ws: Wt 0.66 | Qh Ql Kh Kl Vr Vt 6x1MB | PO 2.79MB = 9.73MB total.
// ---------------------------------------------------------------------------

typedef float f32x4  __attribute__((ext_vector_type(4)));
typedef short bf16x8 __attribute__((ext_vector_type(8)));

__device__ __forceinline__ ushort f2bf(float v) {
    union { float f; unsigned u; } t; t.f = v;
    unsigned r = t.u + 0x7FFFu + ((t.u >> 16) & 1u);   // RNE
    return (ushort)(r >> 16);
}
__device__ __forceinline__ float bf2f(ushort h) {
    union { float f; unsigned u; } t; t.u = ((unsigned)h) << 16;
    return t.f;
}
__device__ __forceinline__ uint4 pack8(const ushort* o) {
    uint4 u;
    u.x = (unsigned)o[0] | ((unsigned)o[1] << 16);
    u.y = (unsigned)o[2] | ((unsigned)o[3] << 16);
    u.z = (unsigned)o[4] | ((unsigned)o[5] << 16);
    u.w = (unsigned)o[6] | ((unsigned)o[7] << 16);
    return u;
}

// ---------------------------------------------------------------------------
// prep_w: slice s<32: f=s>>2 (Q:0-3,K:4-7), hl=(s>>1)&1, ks=s&1;
// s>=32: f=8+((s-32)>>1) (V), hl=0, ks=(s-32)&1.
// cell: Wt[(g*40+s)*512 + l*8] = split(W[col=(f&3)*16+(l&15)][g*64+ks*32+(l>>4)*8])
// ---------------------------------------------------------------------------
__global__ __launch_bounds__(256)
void prep_w(const float* __restrict__ Wq, const float* __restrict__ Wk,
            const float* __restrict__ Wv, ushort* __restrict__ Wt)
{
    const int id = blockIdx.x * 256 + threadIdx.x;   // 0..40959
    const int g  = id / 2560;
    const int r1 = id - g * 2560;
    const int s  = r1 >> 6, l = r1 & 63;
    int f, hl, ks;
    if (s < 32) { f = s >> 2; hl = (s >> 1) & 1; ks = s & 1; }
    else        { int t = s - 32; f = 8 + (t >> 1); hl = 0; ks = t & 1; }
    const float* W = (f < 4) ? Wq : (f < 8) ? Wk : Wv;
    const int col = (f & 3) * 16 + (l & 15);
    const int k   = g * 64 + ks * 32 + (l >> 4) * 8;
    float4 v0 = *(const float4*)&W[(size_t)col * EMBED + k];
    float4 v1 = *(const float4*)&W[(size_t)col * EMBED + k + 4];
    const float vv[8] = {v0.x, v0.y, v0.z, v0.w, v1.x, v1.y, v1.z, v1.w};
    ushort o[8];
#pragma unroll
    for (int i = 0; i < 8; ++i) {
        const ushort h = f2bf(vv[i]);
        o[i] = hl ? f2bf(vv[i] - bf2f(h)) : h;
    }
    *(uint4*)&Wt[((size_t)g * 40 + s) * 512 + l * 8] = pack8(o);
}

// ---------------------------------------------------------------------------
// qkv_fused: 16 rows x 192 cols x K=1024 per block. 4 waves; wave w owns
// output cols [16w,16w+16) of Q (frag w), K (frag w+4), V (frag w+8).
// W frags read global->reg per chunk; x staged in dbuf LDS (1 barrier/chunk).
// ---------------------------------------------------------------------------
__global__ __launch_bounds__(256)
void qkv_fused(const float* __restrict__ x, const ushort* __restrict__ Wt,
               ushort* __restrict__ Qh, ushort* __restrict__ Ql,
               ushort* __restrict__ Kh, ushort* __restrict__ Kl,
               ushort* __restrict__ Vr)
{
    __shared__ ushort SA[2][4 * 512];     // x tile: [hl*2+ks][oc*128+row*8]
    __shared__ float  T[3 * 16 * 68];     // epilogue scratch (13KB)

    const int tid  = threadIdx.x;
    const int w    = tid >> 6;
    const int lane = tid & 63;
    const int row0 = blockIdx.x * 16;

    // x staging identities (tid<128): 16 rows x 8 k-octets
    const int  srow = tid >> 3, so8 = tid & 7;
    const int  sks  = so8 >> 2, soc = so8 & 3;
    const bool sact = (tid < 128);

    f32x4 acc[3];
#pragma unroll
    for (int fi = 0; fi < 3; ++fi) acc[fi] = (f32x4){0.f, 0.f, 0.f, 0.f};

    float4 xa, xb;
    // ---- prologue: load + commit chunk 0 x ----
    if (sact) {
        const float* xp = &x[(size_t)(row0 + srow) * EMBED + so8 * 8];
        xa = *(const float4*)xp; xb = *(const float4*)(xp + 4);
        const float vv[8] = {xa.x, xa.y, xa.z, xa.w, xb.x, xb.y, xb.z, xb.w};
        ushort hs[8], ls[8];
#pragma unroll
        for (int i = 0; i < 8; ++i) { hs[i] = f2bf(vv[i]); ls[i] = f2bf(vv[i] - bf2f(hs[i])); }
        const int base = soc * 128 + srow * 8;
        *(uint4*)&SA[0][sks * 512 + base]       = pack8(hs);
        *(uint4*)&SA[0][(2 + sks) * 512 + base] = pack8(ls);
    }
    __syncthreads();

    for (int c = 0; c < 16; ++c) {
        const int cur = c & 1;
        // ---- issue next chunk's x loads ----
        if (c + 1 < 16 && sact) {
            const float* xp = &x[(size_t)(row0 + srow) * EMBED + (c + 1) * 64 + so8 * 8];
            xa = *(const float4*)xp; xb = *(const float4*)(xp + 4);
        }
        // ---- W frags: global -> registers (1KB contiguous per wave-load) ----
        const ushort* Wg = &Wt[((size_t)c * 40) * 512 + lane * 8];
        bf16x8 qhf[2], qlf[2], khf[2], klf[2], vhf[2];
#pragma unroll
        for (int ks = 0; ks < 2; ++ks) {
            qhf[ks] = *(const bf16x8*)&Wg[(size_t)(w * 4 + ks) * 512];
            qlf[ks] = *(const bf16x8*)&Wg[(size_t)(w * 4 + 2 + ks) * 512];
            khf[ks] = *(const bf16x8*)&Wg[(size_t)((w + 4) * 4 + ks) * 512];
            klf[ks] = *(const bf16x8*)&Wg[(size_t)((w + 4) * 4 + 2 + ks) * 512];
            vhf[ks] = *(const bf16x8*)&Wg[(size_t)(32 + w * 2 + ks) * 512];
        }
        // ---- MFMA on current x buffer ----
#pragma unroll
        for (int ks = 0; ks < 2; ++ks) {
            bf16x8 ah = *(const bf16x8*)&SA[cur][ks * 512 + lane * 8];
            bf16x8 al = *(const bf16x8*)&SA[cur][(2 + ks) * 512 + lane * 8];
            acc[0] = __builtin_amdgcn_mfma_f32_16x16x32_bf16(ah, qhf[ks], acc[0], 0, 0, 0);
            acc[0] = __builtin_amdgcn_mfma_f32_16x16x32_bf16(ah, qlf[ks], acc[0], 0, 0, 0);
            acc[0] = __builtin_amdgcn_mfma_f32_16x16x32_bf16(al, qhf[ks], acc[0], 0, 0, 0);
            acc[1] = __builtin_amdgcn_mfma_f32_16x16x32_bf16(ah, khf[ks], acc[1], 0, 0, 0);
            acc[1] = __builtin_amdgcn_mfma_f32_16x16x32_bf16(ah, klf[ks], acc[1], 0, 0, 0);
            acc[1] = __builtin_amdgcn_mfma_f32_16x16x32_bf16(al, khf[ks], acc[1], 0, 0, 0);
            acc[2] = __builtin_amdgcn_mfma_f32_16x16x32_bf16(ah, vhf[ks], acc[2], 0, 0, 0);
        }
        // ---- commit staged x to the other buffer ----
        if (c + 1 < 16 && sact) {
            const float vv[8] = {xa.x, xa.y, xa.z, xa.w, xb.x, xb.y, xb.z, xb.w};
            ushort hs[8], ls[8];
#pragma unroll
            for (int i = 0; i < 8; ++i) { hs[i] = f2bf(vv[i]); ls[i] = f2bf(vv[i] - bf2f(hs[i])); }
            const int base = soc * 128 + srow * 8;
            *(uint4*)&SA[cur ^ 1][sks * 512 + base]       = pack8(hs);
            *(uint4*)&SA[cur ^ 1][(2 + sks) * 512 + base] = pack8(ls);
        }
        __syncthreads();
    }

    // ---- epilogue: acc -> T -> final bf16 outputs (dense 128B-line writes) --
    // D frag: row = 4*(lane>>4)+r, col(within 16-group) = lane&15.
#pragma unroll
    for (int fi = 0; fi < 3; ++fi)
#pragma unroll
        for (int r = 0; r < 4; ++r)
            T[(fi * 16 + 4 * (lane >> 4) + r) * 68 + w * 16 + (lane & 15)] = acc[fi][r];
    __syncthreads();

    const int orow = tid >> 4, oc4 = tid & 15;
    const size_t obase = (size_t)(row0 + orow) * HEAD + oc4 * 4;
    {   // Q: scale 32, split
        float4 v = *(const float4*)&T[(orow) * 68 + oc4 * 4];
        const float vv[4] = {32.f * v.x, 32.f * v.y, 32.f * v.z, 32.f * v.w};
        ushort h[4], l[4];
#pragma unroll
        for (int i = 0; i < 4; ++i) { h[i] = f2bf(vv[i]); l[i] = f2bf(vv[i] - bf2f(h[i])); }
        *(ushort4*)&Qh[obase] = make_ushort4(h[0], h[1], h[2], h[3]);
        *(ushort4*)&Ql[obase] = make_ushort4(l[0], l[1], l[2], l[3]);
    }
    {   // K: split
        float4 v = *(const float4*)&T[(16 + orow) * 68 + oc4 * 4];
        const float vv[4] = {v.x, v.y, v.z, v.w};
        ushort h[4], l[4];
#pragma unroll
        for (int i = 0; i < 4; ++i) { h[i] = f2bf(vv[i]); l[i] = f2bf(vv[i] - bf2f(h[i])); }
        *(ushort4*)&Kh[obase] = make_ushort4(h[0], h[1], h[2], h[3]);
        *(ushort4*)&Kl[obase] = make_ushort4(l[0], l[1], l[2], l[3]);
    }
    {   // V: hi only, row-major
        float4 v = *(const float4*)&T[(32 + orow) * 68 + oc4 * 4];
        *(ushort4*)&Vr[obase] =
            make_ushort4(f2bf(v.x), f2bf(v.y), f2bf(v.z), f2bf(v.w));
    }
}

// ---------------------------------------------------------------------------
// v_transpose: Vr bf16 [t][d] -> Vt bf16 [b][d][t]. 32 blocks x 256 t-chunk.
// ---------------------------------------------------------------------------
__global__ __launch_bounds__(256)
void v_transpose(const ushort* __restrict__ Vr, ushort* __restrict__ Vt)
{
    __shared__ ushort T2[64][264];
    const int s  = blockIdx.x;            // 0..31
    const int b  = s >> 3;
    const int k0 = (s & 7) * 256;
    const int tid = threadIdx.x;
#pragma unroll
    for (int i = 0; i < 8; ++i) {
        const int u = tid + 256 * i;      // 0..2047
        const int row = u >> 3, c8 = u & 7;
        uint4 v = *(const uint4*)&Vr[((size_t)(b * SEQ + k0 + row)) * HEAD + c8 * 8];
        const ushort* e = (const ushort*)&v;
#pragma unroll
        for (int j = 0; j < 8; ++j) T2[c8 * 8 + j][row] = e[j];
    }
    __syncthreads();
#pragma unroll
    for (int i = 0; i < 8; ++i) {
        const int u = tid + 256 * i;      // 0..2047
        const int d = u >> 5, c8 = u & 31;
        uint4 val = *(const uint4*)&T2[d][c8 * 8];
        *(uint4*)&Vt[((size_t)(b * 64 + d)) * SEQ + k0 + c8 * 8] = val;
    }
}

// ---------------------------------------------------------------------------
// attn_mfma (verified): 2 waves x 16q, 64-key swizzled LDS tiles; swapped
// QK^T -> lane-local softmax; P via swizzled LDS to PV A-frag.
// ---------------------------------------------------------------------------
__global__ __launch_bounds__(128)
void attn_mfma(const ushort* __restrict__ Qh, const ushort* __restrict__ Ql,
               const ushort* __restrict__ Kh, const ushort* __restrict__ Kl,
               const ushort* __restrict__ Vt, char* __restrict__ PO)
{
    const int id = blockIdx.x;            // 0..639
    const int b  = id / 160;
    const int f  = id - 160 * b;
    int G, u;
    if (f < 16)      { G = 0; u = f; }
    else if (f < 48) { G = 1; u = f - 16; }
    else if (f < 96) { G = 2; u = f - 48; }
    else             { G = 3; u = f - 96; }
    const int qb  = 16 * G + u / (G + 1);
    const int kc  = u % (G + 1);
    const int q0  = qb * 32;
    const int ktd = qb >> 1;
    const int nt  = ktd + 1;
    const int t0  = kc * 8;
    const int t1  = (t0 + 8 < nt) ? t0 + 8 : nt;

    const int tid = threadIdx.x;
    const int w   = tid >> 6;
    const int lane = tid & 63;
    const int g = lane >> 4, c = lane & 15;
    const int swz = (c & 7) << 3;

    __shared__ ushort KH[64 * 64];
    __shared__ ushort KL[64 * 64];
    __shared__ ushort VT[64 * 64];
    __shared__ ushort PS[2][16 * 64];

    const int qrow = q0 + 16 * w + c;
    bf16x8 qh[2], ql[2];
#pragma unroll
    for (int ks = 0; ks < 2; ++ks) {
        const size_t qi = ((size_t)(b * SEQ + qrow)) * HEAD + 32 * ks + 8 * g;
        qh[ks] = *(const bf16x8*)&Qh[qi];
        ql[ks] = *(const bf16x8*)&Ql[qi];
    }

    f32x4 o[4];
#pragma unroll
    for (int db = 0; db < 4; ++db) o[db] = (f32x4){0.f, 0.f, 0.f, 0.f};
    float m = -1e30f, lsum = 0.f;

    for (int kt = t0; kt < t1; ++kt) {
        const int kb0 = kt * 64;
        __syncthreads();
#pragma unroll
        for (int i = 0; i < 4; ++i) {
            const int u2  = tid + 128 * i;
            const int row = u2 >> 3, c8 = u2 & 7;
            const int dst = row * 64 + ((c8 ^ (row & 7)) * 8);
            const size_t ksrc = ((size_t)(b * SEQ + kb0 + row)) * HEAD + c8 * 8;
            *(uint4*)&KH[dst] = *(const uint4*)&Kh[ksrc];
            *(uint4*)&KL[dst] = *(const uint4*)&Kl[ksrc];
            const size_t vsrc = ((size_t)(b * 64 + row)) * SEQ + kb0 + c8 * 8;
            *(uint4*)&VT[dst] = *(const uint4*)&Vt[vsrc];
        }
        __syncthreads();

        f32x4 s[4];
#pragma unroll
        for (int kb = 0; kb < 4; ++kb) s[kb] = (f32x4){0.f, 0.f, 0.f, 0.f};
#pragma unroll
        for (int ks = 0; ks < 2; ++ks) {
            const int co = (32 * ks + 8 * g) ^ swz;
#pragma unroll
            for (int kb = 0; kb < 4; ++kb) {
                const int row = 16 * kb + c;
                bf16x8 ah = *(const bf16x8*)&KH[row * 64 + co];
                bf16x8 al = *(const bf16x8*)&KL[row * 64 + co];
                s[kb] = __builtin_amdgcn_mfma_f32_16x16x32_bf16(ah, qh[ks], s[kb], 0, 0, 0);
                s[kb] = __builtin_amdgcn_mfma_f32_16x16x32_bf16(ah, ql[ks], s[kb], 0, 0, 0);
                s[kb] = __builtin_amdgcn_mfma_f32_16x16x32_bf16(al, qh[ks], s[kb], 0, 0, 0);
            }
        }

        if (kt == ktd) {
#pragma unroll
            for (int kb = 0; kb < 4; ++kb)
#pragma unroll
                for (int r = 0; r < 4; ++r)
                    if (kb0 + 16 * kb + 4 * g + r > qrow) s[kb][r] = -1e30f;
        }

        float tmax = -1e30f;
#pragma unroll
        for (int kb = 0; kb < 4; ++kb) {
            float a = fmaxf(fmaxf(s[kb][0], s[kb][1]), fmaxf(s[kb][2], s[kb][3]));
            tmax = fmaxf(tmax, a);
        }
        tmax = fmaxf(tmax, __shfl_xor(tmax, 16));
        tmax = fmaxf(tmax, __shfl_xor(tmax, 32));
        const float mnew = fmaxf(m, tmax);
        const float fac  = __expf(m - mnew);
        float p[4][4];
        float psum = 0.f;
#pragma unroll
        for (int kb = 0; kb < 4; ++kb)
#pragma unroll
            for (int r = 0; r < 4; ++r) {
                p[kb][r] = __expf(s[kb][r] - mnew);
                psum += p[kb][r];
            }
        psum += __shfl_xor(psum, 16);
        psum += __shfl_xor(psum, 32);
        lsum = lsum * fac + psum;
        m = mnew;

        float fb[4];
#pragma unroll
        for (int r = 0; r < 4; ++r) fb[r] = __shfl(fac, 4 * g + r);
#pragma unroll
        for (int db = 0; db < 4; ++db) {
            o[db][0] *= fb[0]; o[db][1] *= fb[1];
            o[db][2] *= fb[2]; o[db][3] *= fb[3];
        }

#pragma unroll
        for (int kb = 0; kb < 4; ++kb) {
            const int idx = c * 64 + (((16 * kb + 4 * g)) ^ swz);
            *(ushort4*)&PS[w][idx] = make_ushort4(
                f2bf(p[kb][0]), f2bf(p[kb][1]), f2bf(p[kb][2]), f2bf(p[kb][3]));
        }

#pragma unroll
        for (int k2 = 0; k2 < 2; ++k2) {
            const int co = (32 * k2 + 8 * g) ^ swz;
            bf16x8 pa = *(const bf16x8*)&PS[w][c * 64 + co];
#pragma unroll
            for (int db = 0; db < 4; ++db) {
                const int row = 16 * db + c;
                bf16x8 vb = *(const bf16x8*)&VT[row * 64 + co];
                o[db] = __builtin_amdgcn_mfma_f32_16x16x32_bf16(pa, vb, o[db], 0, 0, 0);
            }
        }
    }

    // ---- epilogue: po -> KH-as-scratch -> coalesced uint4 copy ----
    char* item = PO + (size_t)id * 4352;
    ushort* po = (ushort*)item;
    float*  ml = (float*)(item + 4096);
    __syncthreads();
    ushort* OT = KH;
#pragma unroll
    for (int db = 0; db < 4; ++db)
#pragma unroll
        for (int r = 0; r < 4; ++r) {
            const int qq = 16 * w + 4 * g + r;
            OT[qq * 64 + 16 * db + c] = f2bf(o[db][r]);
        }
    if (g == 0) {
        ml[16 * w + c]      = m;
        ml[32 + 16 * w + c] = lsum;
    }
    __syncthreads();
#pragma unroll
    for (int i = 0; i < 2; ++i) {
        const int u2 = tid + 128 * i;
        *(uint4*)&po[u2 * 8] = *(const uint4*)&OT[u2 * 8];
    }
}

// ---------------------------------------------------------------------------
__global__ __launch_bounds__(256)
void attn_combine(const char* __restrict__ PO, float* __restrict__ out)
{
    const int qbg = blockIdx.x;            // 0..255
    const int b   = qbg >> 6, qb = qbg & 63;
    const int G   = qb >> 4, np = G + 1;
    const int base = b * 160 + (G + 1) * (qb - 8 * G);
    const int tid = threadIdx.x;
    const int row = tid >> 3, c8 = tid & 7;

    float M = -1e30f;
    for (int p = 0; p < np; ++p) {
        const float* ml = (const float*)(PO + (size_t)(base + p) * 4352 + 4096);
        M = fmaxf(M, ml[row]);
    }
    float L = 0.f;
    float acc[8];
#pragma unroll
    for (int j = 0; j < 8; ++j) acc[j] = 0.f;
    for (int p = 0; p < np; ++p) {
        const char* item = PO + (size_t)(base + p) * 4352;
        const float* ml  = (const float*)(item + 4096);
        const float wgt  = __expf(ml[row] - M);
        L += wgt * ml[32 + row];
        const ushort* po = (const ushort*)item;
        ushort4 a0 = *(const ushort4*)&po[row * 64 + c8 * 8];
        ushort4 a1 = *(const ushort4*)&po[row * 64 + c8 * 8 + 4];
        acc[0] += wgt * bf2f(a0.x); acc[1] += wgt * bf2f(a0.y);
        acc[2] += wgt * bf2f(a0.z); acc[3] += wgt * bf2f(a0.w);
        acc[4] += wgt * bf2f(a1.x); acc[5] += wgt * bf2f(a1.y);
        acc[6] += wgt * bf2f(a1.z); acc[7] += wgt * bf2f(a1.w);
    }
    const float inv = 1.f / L;
    float* dst = &out[((size_t)(b * SEQ + qb * 32 + row)) * HEAD + c8 * 8];
    *(float4*)dst       = make_float4(acc[0] * inv, acc[1] * inv, acc[2] * inv, acc[3] * inv);
    *(float4*)(dst + 4) = make_float4(acc[4] * inv, acc[5] * inv, acc[6] * inv, acc[7] * inv);
}

// ---------------------------------------------------------------------------

extern "C" void kernel_launch(void* const* d_in, const int* in_sizes, int n_in,
                              void* d_out, int out_size, void* d_ws, size_t ws_size,
                              hipStream_t stream)
{
    // setup_inputs order: x, Wk, Wq, Wv
    const float* x  = (const float*)d_in[0];
    const float* Wk = (const float*)d_in[1];
    const float* Wq = (const float*)d_in[2];
    const float* Wv = (const float*)d_in[3];

    char* ws = (char*)d_ws;
    // layout (bytes): Wt 655,360 | Qh/Ql/Kh/Kl/Vr/Vt 6 x 1,048,576 | PO 2,785,280
    ushort* Wt = (ushort*)ws;
    ushort* Qh = (ushort*)(ws +  655360);
    ushort* Ql = (ushort*)(ws + 1703936);
    ushort* Kh = (ushort*)(ws + 2752512);
    ushort* Kl = (ushort*)(ws + 3801088);
    ushort* Vr = (ushort*)(ws + 4849664);
    ushort* Vt = (ushort*)(ws + 5898240);
    char*   PO = ws + 6946816;             // total 9,732,096 B

    prep_w      <<<dim3(160), 256, 0, stream>>>(Wq, Wk, Wv, Wt);
    qkv_fused   <<<dim3(512), 256, 0, stream>>>(x, Wt, Qh, Ql, Kh, Kl, Vr);
    v_transpose <<<dim3(32),  256, 0, stream>>>(Vr, Vt);
    attn_mfma   <<<dim3(640), 128, 0, stream>>>(Qh, Ql, Kh, Kl, Vt, PO);
    attn_combine<<<dim3(256), 256, 0, stream>>>(PO, (float*)d_out);
}